// Round 1
// baseline (5262.035 us; speedup 1.0000x reference)
//
#include <hip/hip_runtime.h>
#include <math.h>

// Problem constants
static constexpr int NB  = 64;     // batch
static constexpr int L0  = 8192;   // input length
static constexpr int L1  = 4096;   // after ec1
static constexpr int LQ  = 2048;   // latent length
static constexpr int CH  = 128;    // hidden H
static constexpr int CHH = 64;     // H/2
static constexpr int CR  = 32;     // residual hidden
static constexpr int CD  = 64;     // codebook dim D
static constexpr int NK  = 512;    // codebook size K
static constexpr int NROWS = NB * LQ;  // 131072 latent vectors

// ---------------- ec1: [B,1,8192] -> [B,64,4096], k4 s2 p1, bias+ReLU ----------------
__global__ __launch_bounds__(256) void k_ec1(const float* __restrict__ x,
                                             const float* __restrict__ w,
                                             const float* __restrict__ bias,
                                             float* __restrict__ out) {
    int n = blockIdx.x * 256 + threadIdx.x;       // over B*64*4096
    int t  = n & (L1 - 1);
    int co = (n >> 12) & (CHH - 1);
    int b  = n >> 18;
    const float* xp = x + b * L0;
    float acc = bias[co];
    int p0 = 2 * t - 1;
#pragma unroll
    for (int k = 0; k < 4; ++k) {
        int p = p0 + k;
        if (p >= 0 && p < L0) acc += w[co * 4 + k] * xp[p];
    }
    out[n] = fmaxf(acc, 0.f);
}

// ---------------- ec2: [B,64,4096] -> [B,128,2048], k4 s2 p1, bias+ReLU ----------------
__global__ __launch_bounds__(256) void k_ec2(const float* __restrict__ x,
                                             const float* __restrict__ w,
                                             const float* __restrict__ bias,
                                             float* __restrict__ out) {
    __shared__ float xs[64][132];
    int t0 = blockIdx.x * 64;
    int co0 = blockIdx.y * 4;
    int b = blockIdx.z;
    int tid = threadIdx.x;
    for (int i = tid; i < 64 * 132; i += 256) {
        int ci = i / 132, j = i - ci * 132;
        int p = 2 * t0 - 1 + j;
        xs[ci][j] = (p >= 0 && p < L1) ? x[(b * 64 + ci) * L1 + p] : 0.f;
    }
    __syncthreads();
    int dt = tid & 63;
    int co = co0 + (tid >> 6);
    const float* wp = w + co * 256;               // [ci][k], k=4
    float acc = bias[co];
#pragma unroll 8
    for (int ci = 0; ci < 64; ++ci) {
        const float2* row = reinterpret_cast<const float2*>(&xs[ci][0]);
        float2 a = row[dt];                       // elems 2dt, 2dt+1
        float2 c = row[dt + 1];                   // elems 2dt+2, 2dt+3
        acc += wp[ci * 4 + 0] * a.x + wp[ci * 4 + 1] * a.y
             + wp[ci * 4 + 2] * c.x + wp[ci * 4 + 3] * c.y;
    }
    out[(b * CH + co) * LQ + t0 + dt] = fmaxf(acc, 0.f);
}

// ---------------- generic k3 p1 conv, channel-major in/out ----------------
template <int CIN, int COUT, bool RELU_IN, bool HAS_BIAS>
__global__ __launch_bounds__(256) void k_conv3(const float* __restrict__ x,
                                               const float* __restrict__ w,
                                               const float* __restrict__ bias,
                                               float* __restrict__ out) {
    __shared__ float xs[CIN][66];
    int t0 = blockIdx.x * 64;
    int co0 = blockIdx.y * 4;
    int b = blockIdx.z;
    int tid = threadIdx.x;
    for (int i = tid; i < CIN * 66; i += 256) {
        int ci = i / 66, j = i - ci * 66;
        int p = t0 - 1 + j;
        float v = (p >= 0 && p < LQ) ? x[(b * CIN + ci) * LQ + p] : 0.f;
        if (RELU_IN) v = fmaxf(v, 0.f);
        xs[ci][j] = v;
    }
    __syncthreads();
    int dt = tid & 63;
    int co = co0 + (tid >> 6);
    const float* wp = w + co * (CIN * 3);
    float acc = HAS_BIAS ? bias[co] : 0.f;
    for (int ci = 0; ci < CIN; ++ci) {
        float x0 = xs[ci][dt];
        float x1 = xs[ci][dt + 1];
        float x2 = xs[ci][dt + 2];
        acc += wp[ci * 3 + 0] * x0 + wp[ci * 3 + 1] * x1 + wp[ci * 3 + 2] * x2;
    }
    out[(b * COUT + co) * LQ + t0 + dt] = acc;
}

// ---------------- residual second conv: x += W2 @ relu(h), k=1, 32->128 ----------------
__global__ __launch_bounds__(256) void k_resadd(const float* __restrict__ h,
                                                const float* __restrict__ w2,
                                                float* __restrict__ x) {
    int n = blockIdx.x * 256 + threadIdx.x;       // over B*128*2048
    int t  = n & (LQ - 1);
    int co = (n >> 11) & (CH - 1);
    int b  = n >> 18;
    const float* hp = h + b * CR * LQ + t;
    const float* wp = w2 + co * CR;
    float acc = 0.f;
#pragma unroll
    for (int ci = 0; ci < CR; ++ci)
        acc += wp[ci] * fmaxf(hp[ci * LQ], 0.f);
    x[n] += acc;
}

// ---------------- pvq: z[b,t,d] = bias[d] + sum_ci w[d,ci]*relu(x[b,ci,t]) ----------------
__global__ __launch_bounds__(256) void k_pvq(const float* __restrict__ x,
                                             const float* __restrict__ w,
                                             const float* __restrict__ bias,
                                             float* __restrict__ z) {
    __shared__ float wT[CH][65];                  // wT[ci][d], padded
    int tid = threadIdx.x;
    for (int i = tid; i < CD * CH; i += 256) {
        int d = i >> 7, ci = i & 127;
        wT[ci][d] = w[i];
    }
    __syncthreads();
    int t0 = blockIdx.x * 64;
    int b = blockIdx.y;
    int d = tid & 63;
    int tg = tid >> 6;
    const float* xp = x + b * CH * LQ + t0 + tg * 16;
    float acc[16];
    float bv = bias[d];
#pragma unroll
    for (int i = 0; i < 16; ++i) acc[i] = bv;
    for (int ci = 0; ci < CH; ++ci) {
        float wv = wT[ci][d];
        const float* xr = xp + ci * LQ;
#pragma unroll
        for (int i = 0; i < 16; ++i) acc[i] += wv * fmaxf(xr[i], 0.f);
    }
    int tbase = t0 + tg * 16;
#pragma unroll
    for (int i = 0; i < 16; ++i)
        z[(b * LQ + tbase + i) * CD + d] = acc[i];
}

// ---------------- cb2[k] = |codebook_k|^2 ----------------
__global__ __launch_bounds__(256) void k_cb2(const float* __restrict__ cb,
                                             float* __restrict__ cb2) {
    int k = blockIdx.x * 256 + threadIdx.x;
    if (k >= NK) return;
    const float* r = cb + k * CD;
    float s = 0.f;
#pragma unroll 8
    for (int i = 0; i < CD; ++i) s += r[i] * r[i];
    cb2[k] = s;
}

// ---------------- VQ: argmin + q gather + sse + histogram ----------------
__global__ __launch_bounds__(256) void k_vq(const float* __restrict__ z,
                                            const float* __restrict__ cb,
                                            const float* __restrict__ cb2,
                                            float* __restrict__ q,
                                            int* __restrict__ counts,
                                            float* __restrict__ sse) {
    __shared__ float cs[128][64];                 // codebook chunk
    __shared__ int hist[NK];
    __shared__ float red[256];
    int tid = threadIdx.x;
    int row0 = blockIdx.x * 512 + tid;            // handles row0 and row0+256
    float4 za[16], zb[16];
    const float4* zr0 = reinterpret_cast<const float4*>(z + (size_t)row0 * CD);
    const float4* zr1 = reinterpret_cast<const float4*>(z + (size_t)(row0 + 256) * CD);
#pragma unroll
    for (int i = 0; i < 16; ++i) { za[i] = zr0[i]; zb[i] = zr1[i]; }
    for (int i = tid; i < NK; i += 256) hist[i] = 0;
    float bestA = 1e30f, bestB = 1e30f;
    int idxA = 0, idxB = 0;
    for (int c0 = 0; c0 < NK; c0 += 128) {
        __syncthreads();
        const float4* src = reinterpret_cast<const float4*>(cb + c0 * CD);
        float4* dst = reinterpret_cast<float4*>(&cs[0][0]);
        for (int i = tid; i < 128 * 64 / 4; i += 256) dst[i] = src[i];
        __syncthreads();
        for (int c = 0; c < 128; ++c) {
            const float4* cr = reinterpret_cast<const float4*>(&cs[c][0]);
            float dA = 0.f, dB = 0.f;
#pragma unroll
            for (int i = 0; i < 16; ++i) {
                float4 cv = cr[i];
                dA += cv.x * za[i].x + cv.y * za[i].y + cv.z * za[i].z + cv.w * za[i].w;
                dB += cv.x * zb[i].x + cv.y * zb[i].y + cv.z * zb[i].z + cv.w * zb[i].w;
            }
            float c2 = cb2[c0 + c];
            float sA = c2 - 2.f * dA;
            float sB = c2 - 2.f * dB;
            if (sA < bestA) { bestA = sA; idxA = c0 + c; }
            if (sB < bestB) { bestB = sB; idxB = c0 + c; }
        }
    }
    float err = 0.f;
    {
        const float4* qa = reinterpret_cast<const float4*>(cb + idxA * CD);
        float4* qo = reinterpret_cast<float4*>(q + (size_t)row0 * CD);
#pragma unroll
        for (int i = 0; i < 16; ++i) {
            float4 cv = qa[i]; qo[i] = cv;
            float dx = cv.x - za[i].x, dy = cv.y - za[i].y;
            float dz2 = cv.z - za[i].z, dw = cv.w - za[i].w;
            err += dx * dx + dy * dy + dz2 * dz2 + dw * dw;
        }
        const float4* qb = reinterpret_cast<const float4*>(cb + idxB * CD);
        float4* qo1 = reinterpret_cast<float4*>(q + (size_t)(row0 + 256) * CD);
#pragma unroll
        for (int i = 0; i < 16; ++i) {
            float4 cv = qb[i]; qo1[i] = cv;
            float dx = cv.x - zb[i].x, dy = cv.y - zb[i].y;
            float dz2 = cv.z - zb[i].z, dw = cv.w - zb[i].w;
            err += dx * dx + dy * dy + dz2 * dz2 + dw * dw;
        }
    }
    atomicAdd(&hist[idxA], 1);
    atomicAdd(&hist[idxB], 1);
    red[tid] = err;
    __syncthreads();
    for (int s = 128; s > 0; s >>= 1) {
        if (tid < s) red[tid] += red[tid + s];
        __syncthreads();
    }
    if (tid == 0) atomicAdd(sse, red[0]);
    for (int i = tid; i < NK; i += 256) atomicAdd(&counts[i], hist[i]);
}

// ---------------- dc1: q [B,2048,64] -> [B,128,2048], k3 p1, bias ----------------
__global__ __launch_bounds__(256) void k_dc1(const float* __restrict__ qz,
                                             const float* __restrict__ w,
                                             const float* __restrict__ bias,
                                             float* __restrict__ out) {
    __shared__ float xs[66][65];                  // [l+halo][ci], padded
    int t0 = blockIdx.x * 64;
    int co0 = blockIdx.y * 4;
    int b = blockIdx.z;
    int tid = threadIdx.x;
    for (int i = tid; i < 66 * 64; i += 256) {
        int l = i >> 6, ci = i & 63;
        int p = t0 - 1 + l;
        xs[l][ci] = (p >= 0 && p < LQ) ? qz[((size_t)b * LQ + p) * CD + ci] : 0.f;
    }
    __syncthreads();
    int dt = tid & 63;
    int co = co0 + (tid >> 6);
    const float* wp = w + co * (CD * 3);
    float acc = bias[co];
    for (int ci = 0; ci < CD; ++ci) {
        acc += wp[ci * 3 + 0] * xs[dt][ci]
             + wp[ci * 3 + 1] * xs[dt + 1][ci]
             + wp[ci * 3 + 2] * xs[dt + 2][ci];
    }
    out[(b * CH + co) * LQ + t0 + dt] = acc;
}

// ---------------- dt1: ConvT 128->64 k4 s2 p1, relu(in), relu(out) ----------------
__global__ __launch_bounds__(256) void k_dt1(const float* __restrict__ x,
                                             const float* __restrict__ w,
                                             const float* __restrict__ bias,
                                             float* __restrict__ out) {
    __shared__ float xs[CH][66];
    int u0 = blockIdx.x * 64;
    int o0 = blockIdx.y * 4;
    int b = blockIdx.z;
    int tid = threadIdx.x;
    for (int i = tid; i < CH * 66; i += 256) {
        int ci = i / 66, j = i - ci * 66;
        int p = u0 - 1 + j;
        xs[ci][j] = (p >= 0 && p < LQ) ? fmaxf(x[(b * CH + ci) * LQ + p], 0.f) : 0.f;
    }
    __syncthreads();
    int du = tid & 63;
    int o = o0 + (tid >> 6);
    float bv = bias[o];
    float ae = bv, ao = bv;
    const float* wp = w + o * 4;                  // w[ci*256 + o*4 + k]
    for (int ci = 0; ci < CH; ++ci) {
        float xm  = xs[ci][du];                   // u-1
        float x0  = xs[ci][du + 1];               // u
        float xp1 = xs[ci][du + 2];               // u+1
        const float* wc = wp + ci * 256;
        ae += wc[1] * x0 + wc[3] * xm;            // out[2u]
        ao += wc[0] * xp1 + wc[2] * x0;           // out[2u+1]
    }
    int u = u0 + du;
    float2 r;
    r.x = fmaxf(ae, 0.f);
    r.y = fmaxf(ao, 0.f);
    reinterpret_cast<float2*>(out + (b * CHH + o) * L1)[u] = r;
}

// ---------------- dt2: ConvT 64->1 k4 s2 p1 -> recon ----------------
__global__ __launch_bounds__(256) void k_dt2(const float* __restrict__ x,
                                             const float* __restrict__ w,
                                             const float* __restrict__ bias,
                                             float* __restrict__ out) {
    int u = blockIdx.x * 256 + threadIdx.x;       // 0..4095
    int b = blockIdx.y;
    const float* xp = x + b * CHH * L1 + u;
    float bv = bias[0];
    float ae = bv, ao = bv;
    for (int ci = 0; ci < CHH; ++ci) {
        const float* xr = xp + ci * L1;
        float xm  = (u >= 1) ? xr[-1] : 0.f;
        float x0  = xr[0];
        float xp1 = (u < L1 - 1) ? xr[1] : 0.f;
        const float* wc = w + ci * 4;
        ae += wc[1] * x0 + wc[3] * xm;
        ao += wc[0] * xp1 + wc[2] * x0;
    }
    reinterpret_cast<float2*>(out + (size_t)b * L0)[u] = make_float2(ae, ao);
}

// ---------------- finalize: vq_loss + perplexity ----------------
__global__ __launch_bounds__(512) void k_final(const int* __restrict__ counts,
                                               const float* __restrict__ sse,
                                               float* __restrict__ out) {
    __shared__ float red[8];
    int tid = threadIdx.x;                        // 512 threads
    float p = (float)counts[tid] * (1.f / (float)NROWS);
    float v = p * logf(p + 1e-10f);
#pragma unroll
    for (int s = 32; s > 0; s >>= 1) v += __shfl_down(v, s);
    if ((tid & 63) == 0) red[tid >> 6] = v;
    __syncthreads();
    if (tid == 0) {
        float tot = 0.f;
        for (int i = 0; i < 8; ++i) tot += red[i];
        out[524288] = 1.25f * sse[0] / ((float)NROWS * (float)CD);
        out[524289] = expf(-tot);
    }
}

extern "C" void kernel_launch(void* const* d_in, const int* in_sizes, int n_in,
                              void* d_out, int out_size, void* d_ws, size_t ws_size,
                              hipStream_t stream) {
    const float* x      = (const float*)d_in[0];
    const float* ec1_w  = (const float*)d_in[1];
    const float* ec1_b  = (const float*)d_in[2];
    const float* ec2_w  = (const float*)d_in[3];
    const float* ec2_b  = (const float*)d_in[4];
    const float* ec3_w  = (const float*)d_in[5];
    const float* ec3_b  = (const float*)d_in[6];
    const float* er1_w1 = (const float*)d_in[7];
    const float* er1_w2 = (const float*)d_in[8];
    const float* er2_w1 = (const float*)d_in[9];
    const float* er2_w2 = (const float*)d_in[10];
    const float* pvq_w  = (const float*)d_in[11];
    const float* pvq_b  = (const float*)d_in[12];
    const float* cbk    = (const float*)d_in[13];
    const float* dc1_w  = (const float*)d_in[14];
    const float* dc1_b  = (const float*)d_in[15];
    const float* dr1_w1 = (const float*)d_in[16];
    const float* dr1_w2 = (const float*)d_in[17];
    const float* dr2_w1 = (const float*)d_in[18];
    const float* dr2_w2 = (const float*)d_in[19];
    const float* dt1_w  = (const float*)d_in[20];
    const float* dt1_b  = (const float*)d_in[21];
    const float* dt2_w  = (const float*)d_in[22];
    const float* dt2_b  = (const float*)d_in[23];
    float* out = (float*)d_out;

    // workspace layout: two 64MB ping-pong buffers + scalars
    char* ws = (char*)d_ws;
    float* A    = (float*)(ws);                        // 64 MB
    float* Bb   = (float*)(ws + 67108864);             // 64 MB
    char*  smal = ws + 134217728;
    int*   counts = (int*)smal;                        // 2048 B
    float* sse    = (float*)(smal + 2048);             // 4 B
    float* cb2    = (float*)(smal + 4096);             // 2048 B
    float* z = Bb;                                     // 32 MB  [B,2048,64]
    float* q = Bb + 8388608;                           // 32 MB  [B,2048,64]

    hipMemsetAsync(smal, 0, 2056, stream);

    // encoder
    k_ec1<<<dim3((NB * CHH * L1) / 256), 256, 0, stream>>>(x, ec1_w, ec1_b, A);
    k_ec2<<<dim3(LQ / 64, CH / 4, NB), 256, 0, stream>>>(A, ec2_w, ec2_b, Bb);
    k_conv3<CH, CH, false, true><<<dim3(LQ / 64, CH / 4, NB), 256, 0, stream>>>(Bb, ec3_w, ec3_b, A);
    float* HmidE = Bb;                                 // 16 MB scratch
    k_conv3<CH, CR, true, false><<<dim3(LQ / 64, CR / 4, NB), 256, 0, stream>>>(A, er1_w1, nullptr, HmidE);
    k_resadd<<<dim3((NB * CH * LQ) / 256), 256, 0, stream>>>(HmidE, er1_w2, A);
    k_conv3<CH, CR, true, false><<<dim3(LQ / 64, CR / 4, NB), 256, 0, stream>>>(A, er2_w1, nullptr, HmidE);
    k_resadd<<<dim3((NB * CH * LQ) / 256), 256, 0, stream>>>(HmidE, er2_w2, A);
    k_pvq<<<dim3(LQ / 64, NB), 256, 0, stream>>>(A, pvq_w, pvq_b, z);

    // vector quantizer
    k_cb2<<<dim3(2), 256, 0, stream>>>(cbk, cb2);
    k_vq<<<dim3(NROWS / 512), 256, 0, stream>>>(z, cbk, cb2, q, counts, sse);

    // decoder
    k_dc1<<<dim3(LQ / 64, CH / 4, NB), 256, 0, stream>>>(q, dc1_w, dc1_b, A);
    float* HmidD = Bb;                                 // z dead, q still at Bb+32MB
    k_conv3<CH, CR, true, false><<<dim3(LQ / 64, CR / 4, NB), 256, 0, stream>>>(A, dr1_w1, nullptr, HmidD);
    k_resadd<<<dim3((NB * CH * LQ) / 256), 256, 0, stream>>>(HmidD, dr1_w2, A);
    k_conv3<CH, CR, true, false><<<dim3(LQ / 64, CR / 4, NB), 256, 0, stream>>>(A, dr2_w1, nullptr, HmidD);
    k_resadd<<<dim3((NB * CH * LQ) / 256), 256, 0, stream>>>(HmidD, dr2_w2, A);
    k_dt1<<<dim3(L1 / 128, CHH / 4, NB), 256, 0, stream>>>(A, dt1_w, dt1_b, Bb);
    k_dt2<<<dim3(L1 / 256, NB), 256, 0, stream>>>(Bb, dt2_w, dt2_b, out);

    // scalars
    k_final<<<dim3(1), 512, 0, stream>>>(counts, sse, out);
}

// Round 2
// 2022.777 us; speedup vs baseline: 2.6014x; 2.6014x over previous
//
#include <hip/hip_runtime.h>
#include <math.h>

// Problem constants
static constexpr int NB  = 64;     // batch
static constexpr int L0  = 8192;   // input length
static constexpr int L1  = 4096;   // after ec1
static constexpr int LQ  = 2048;   // latent length
static constexpr int CH  = 128;    // hidden H
static constexpr int CHH = 64;     // H/2
static constexpr int CR  = 32;     // residual hidden
static constexpr int CD  = 64;     // codebook dim D
static constexpr int NK  = 512;    // codebook size K
static constexpr int NROWS = NB * LQ;  // 131072 latent vectors

// ---------------- weight transpose: src[CO][CI][K] -> dst[CI][CO][4] (k-padded) ----------
__global__ __launch_bounds__(256) void k_wt(const float* __restrict__ src,
                                            float* __restrict__ dst,
                                            int CO, int CI, int K) {
    int i = blockIdx.x * 256 + threadIdx.x;
    if (i >= CO * CI) return;
    int co = i / CI, ci = i - co * CI;
    float4 v = make_float4(0.f, 0.f, 0.f, 0.f);
    v.x = src[i * K + 0];
    v.y = src[i * K + 1];
    v.z = src[i * K + 2];
    if (K == 4) v.w = src[i * K + 3];
    reinterpret_cast<float4*>(dst)[ci * CO + co] = v;
}

// ---------------- ec1: [B,1,8192] -> [B,64,4096], k4 s2 p1, bias+ReLU ----------------
__global__ __launch_bounds__(256) void k_ec1(const float* __restrict__ x,
                                             const float* __restrict__ w,
                                             const float* __restrict__ bias,
                                             float* __restrict__ out) {
    int n = blockIdx.x * 256 + threadIdx.x;       // over B*64*4096
    int t  = n & (L1 - 1);
    int co = (n >> 12) & (CHH - 1);
    int b  = n >> 18;
    const float* xp = x + b * L0;
    float acc = bias[co];
    int p0 = 2 * t - 1;
#pragma unroll
    for (int k = 0; k < 4; ++k) {
        int p = p0 + k;
        if (p >= 0 && p < L0) acc += w[co * 4 + k] * xp[p];
    }
    out[n] = fmaxf(acc, 0.f);
}

// ---------------- ec2: [B,64,4096] -> [B,128,2048], k4 s2 p1, bias+ReLU, reg-blocked ----
__global__ __launch_bounds__(256) void k_ec2r(const float* __restrict__ x,
                                              const float* __restrict__ wt,  // [ci][128][4]
                                              const float* __restrict__ bias,
                                              float* __restrict__ out) {
    __shared__ float xs[64][132];
    int t0 = blockIdx.x * 64;
    int b = blockIdx.z;
    int tid = threadIdx.x;
    for (int i = tid; i < 64 * 132; i += 256) {
        int ci = i / 132, j = i - ci * 132;
        int p = 2 * t0 - 1 + j;
        xs[ci][j] = (p >= 0 && p < L1) ? x[(b * 64 + ci) * L1 + p] : 0.f;
    }
    __syncthreads();
    int t = tid & 63;
    int g = __builtin_amdgcn_readfirstlane(tid >> 6);
    int co0 = blockIdx.y * 64 + g * 16;
    float acc[16];
#pragma unroll
    for (int o = 0; o < 16; ++o) acc[o] = bias[co0 + o];
    for (int ci = 0; ci < 64; ++ci) {
        const float2* row = reinterpret_cast<const float2*>(&xs[ci][0]);
        float2 a = row[t];
        float2 c = row[t + 1];
        const float4* wp = reinterpret_cast<const float4*>(wt + (size_t)(ci * CH + co0) * 4);
#pragma unroll
        for (int o = 0; o < 16; ++o) {
            float4 wv = wp[o];
            acc[o] = fmaf(wv.x, a.x, fmaf(wv.y, a.y, fmaf(wv.z, c.x, fmaf(wv.w, c.y, acc[o]))));
        }
    }
#pragma unroll
    for (int o = 0; o < 16; ++o)
        out[((size_t)b * CH + co0 + o) * LQ + t0 + t] = fmaxf(acc[o], 0.f);
}

// ---------------- k3 p1 conv, channel-major, register-blocked outputs ----------------
template <int CIN, int COUT, int OCB, bool RELU_IN, bool HAS_BIAS>
__global__ __launch_bounds__(256) void k_conv3r(const float* __restrict__ x,
                                                const float* __restrict__ wt,  // [ci][COUT][4]
                                                const float* __restrict__ bias,
                                                float* __restrict__ out) {
    constexpr int OCP = OCB / 4;
    __shared__ float xs[CIN][66];
    int t0 = blockIdx.x * 64;
    int b = blockIdx.z;
    int tid = threadIdx.x;
    for (int i = tid; i < CIN * 66; i += 256) {
        int ci = i / 66, j = i - ci * 66;
        int p = t0 - 1 + j;
        float v = (p >= 0 && p < LQ) ? x[(b * CIN + ci) * LQ + p] : 0.f;
        if (RELU_IN) v = fmaxf(v, 0.f);
        xs[ci][j] = v;
    }
    __syncthreads();
    int t = tid & 63;
    int g = __builtin_amdgcn_readfirstlane(tid >> 6);
    int co0 = blockIdx.y * OCB + g * OCP;
    float acc[OCP];
#pragma unroll
    for (int o = 0; o < OCP; ++o) acc[o] = HAS_BIAS ? bias[co0 + o] : 0.f;
    for (int ci = 0; ci < CIN; ++ci) {
        float x0 = xs[ci][t];
        float x1 = xs[ci][t + 1];
        float x2 = xs[ci][t + 2];
        const float4* wp = reinterpret_cast<const float4*>(wt + (size_t)(ci * COUT + co0) * 4);
#pragma unroll
        for (int o = 0; o < OCP; ++o) {
            float4 wv = wp[o];
            acc[o] = fmaf(wv.x, x0, fmaf(wv.y, x1, fmaf(wv.z, x2, acc[o])));
        }
    }
#pragma unroll
    for (int o = 0; o < OCP; ++o)
        out[((size_t)b * COUT + co0 + o) * LQ + t0 + t] = acc[o];
}

// ---------------- residual second conv: x += W2 @ relu(h), k=1, 32->128 ----------------
__global__ __launch_bounds__(256) void k_resadd(const float* __restrict__ h,
                                                const float* __restrict__ w2,
                                                float* __restrict__ x) {
    int n = blockIdx.x * 256 + threadIdx.x;       // over B*128*2048
    int t  = n & (LQ - 1);
    int co = (n >> 11) & (CH - 1);
    int b  = n >> 18;
    const float* hp = h + b * CR * LQ + t;
    const float* wp = w2 + co * CR;
    float acc = 0.f;
#pragma unroll
    for (int ci = 0; ci < CR; ++ci)
        acc += wp[ci] * fmaxf(hp[ci * LQ], 0.f);
    x[n] += acc;
}

// ---------------- pvq: z[b,t,d] = bias[d] + sum_ci w[d,ci]*relu(x[b,ci,t]) ----------------
__global__ __launch_bounds__(256) void k_pvqr(const float* __restrict__ x,
                                              const float* __restrict__ w,
                                              const float* __restrict__ bias,
                                              float* __restrict__ z) {
    __shared__ float xs[CH][64];
    __shared__ float wT[CH][64];
    int tid = threadIdx.x;
    int t0 = blockIdx.x * 64;
    int b = blockIdx.y;
    for (int i = tid; i < CD * CH; i += 256) {
        int d = i >> 7, ci = i & 127;
        wT[ci][d] = w[i];
    }
    for (int i = tid; i < CH * 64; i += 256) {
        int ci = i >> 6, j = i & 63;
        xs[ci][j] = fmaxf(x[((size_t)b * CH + ci) * LQ + t0 + j], 0.f);
    }
    __syncthreads();
    int d = tid & 63;
    int tg = tid >> 6;                            // 4 groups x 16 t
    float bv = bias[d];
    float acc[16];
#pragma unroll
    for (int i = 0; i < 16; ++i) acc[i] = bv;
    for (int ci = 0; ci < CH; ++ci) {
        float wv = wT[ci][d];
        const float4* xr = reinterpret_cast<const float4*>(&xs[ci][tg * 16]);
        float4 a = xr[0], bq = xr[1], c = xr[2], e = xr[3];
        acc[0]  = fmaf(wv, a.x, acc[0]);
        acc[1]  = fmaf(wv, a.y, acc[1]);
        acc[2]  = fmaf(wv, a.z, acc[2]);
        acc[3]  = fmaf(wv, a.w, acc[3]);
        acc[4]  = fmaf(wv, bq.x, acc[4]);
        acc[5]  = fmaf(wv, bq.y, acc[5]);
        acc[6]  = fmaf(wv, bq.z, acc[6]);
        acc[7]  = fmaf(wv, bq.w, acc[7]);
        acc[8]  = fmaf(wv, c.x, acc[8]);
        acc[9]  = fmaf(wv, c.y, acc[9]);
        acc[10] = fmaf(wv, c.z, acc[10]);
        acc[11] = fmaf(wv, c.w, acc[11]);
        acc[12] = fmaf(wv, e.x, acc[12]);
        acc[13] = fmaf(wv, e.y, acc[13]);
        acc[14] = fmaf(wv, e.z, acc[14]);
        acc[15] = fmaf(wv, e.w, acc[15]);
    }
    int tbase = t0 + tg * 16;
#pragma unroll
    for (int i = 0; i < 16; ++i)
        z[((size_t)b * LQ + tbase + i) * CD + d] = acc[i];
}

// ---------------- cb2[k] = |codebook_k|^2 ----------------
__global__ __launch_bounds__(256) void k_cb2(const float* __restrict__ cb,
                                             float* __restrict__ cb2) {
    int k = blockIdx.x * 256 + threadIdx.x;
    if (k >= NK) return;
    const float* r = cb + k * CD;
    float s = 0.f;
#pragma unroll 8
    for (int i = 0; i < CD; ++i) s += r[i] * r[i];
    cb2[k] = s;
}

// ---------------- VQ: argmin + q gather + sse + histogram ----------------
__global__ __launch_bounds__(256) void k_vq(const float* __restrict__ z,
                                            const float* __restrict__ cb,
                                            const float* __restrict__ cb2,
                                            float* __restrict__ q,
                                            int* __restrict__ counts,
                                            float* __restrict__ sse) {
    __shared__ float cs[128][64];                 // codebook chunk
    __shared__ int hist[NK];
    __shared__ float red[256];
    int tid = threadIdx.x;
    int row0 = blockIdx.x * 512 + tid;            // handles row0 and row0+256
    float4 za[16], zb[16];
    const float4* zr0 = reinterpret_cast<const float4*>(z + (size_t)row0 * CD);
    const float4* zr1 = reinterpret_cast<const float4*>(z + (size_t)(row0 + 256) * CD);
#pragma unroll
    for (int i = 0; i < 16; ++i) { za[i] = zr0[i]; zb[i] = zr1[i]; }
    for (int i = tid; i < NK; i += 256) hist[i] = 0;
    float bestA = 1e30f, bestB = 1e30f;
    int idxA = 0, idxB = 0;
    for (int c0 = 0; c0 < NK; c0 += 128) {
        __syncthreads();
        const float4* src = reinterpret_cast<const float4*>(cb + c0 * CD);
        float4* dst = reinterpret_cast<float4*>(&cs[0][0]);
        for (int i = tid; i < 128 * 64 / 4; i += 256) dst[i] = src[i];
        __syncthreads();
        for (int c = 0; c < 128; ++c) {
            const float4* cr = reinterpret_cast<const float4*>(&cs[c][0]);
            float dA = 0.f, dB = 0.f;
#pragma unroll
            for (int i = 0; i < 16; ++i) {
                float4 cv = cr[i];
                dA += cv.x * za[i].x + cv.y * za[i].y + cv.z * za[i].z + cv.w * za[i].w;
                dB += cv.x * zb[i].x + cv.y * zb[i].y + cv.z * zb[i].z + cv.w * zb[i].w;
            }
            float c2 = cb2[c0 + c];
            float sA = c2 - 2.f * dA;
            float sB = c2 - 2.f * dB;
            if (sA < bestA) { bestA = sA; idxA = c0 + c; }
            if (sB < bestB) { bestB = sB; idxB = c0 + c; }
        }
    }
    float err = 0.f;
    {
        const float4* qa = reinterpret_cast<const float4*>(cb + idxA * CD);
        float4* qo = reinterpret_cast<float4*>(q + (size_t)row0 * CD);
#pragma unroll
        for (int i = 0; i < 16; ++i) {
            float4 cv = qa[i]; qo[i] = cv;
            float dx = cv.x - za[i].x, dy = cv.y - za[i].y;
            float dz2 = cv.z - za[i].z, dw = cv.w - za[i].w;
            err += dx * dx + dy * dy + dz2 * dz2 + dw * dw;
        }
        const float4* qb = reinterpret_cast<const float4*>(cb + idxB * CD);
        float4* qo1 = reinterpret_cast<float4*>(q + (size_t)(row0 + 256) * CD);
#pragma unroll
        for (int i = 0; i < 16; ++i) {
            float4 cv = qb[i]; qo1[i] = cv;
            float dx = cv.x - zb[i].x, dy = cv.y - zb[i].y;
            float dz2 = cv.z - zb[i].z, dw = cv.w - zb[i].w;
            err += dx * dx + dy * dy + dz2 * dz2 + dw * dw;
        }
    }
    atomicAdd(&hist[idxA], 1);
    atomicAdd(&hist[idxB], 1);
    red[tid] = err;
    __syncthreads();
    for (int s = 128; s > 0; s >>= 1) {
        if (tid < s) red[tid] += red[tid + s];
        __syncthreads();
    }
    if (tid == 0) atomicAdd(sse, red[0]);
    for (int i = tid; i < NK; i += 256) atomicAdd(&counts[i], hist[i]);
}

// ---------------- dc1: q [B,2048,64] -> [B,128,2048], k3 p1, bias, reg-blocked ----------
__global__ __launch_bounds__(256) void k_dc1r(const float* __restrict__ qz,
                                              const float* __restrict__ wt,  // [ci][128][4]
                                              const float* __restrict__ bias,
                                              float* __restrict__ out) {
    __shared__ float xs[CD][67];
    int t0 = blockIdx.x * 64;
    int b = blockIdx.z;
    int tid = threadIdx.x;
    for (int i = tid; i < 66 * 64; i += 256) {
        int l = i >> 6, ci = i & 63;
        int p = t0 - 1 + l;
        xs[ci][l] = (p >= 0 && p < LQ) ? qz[((size_t)b * LQ + p) * CD + ci] : 0.f;
    }
    __syncthreads();
    int t = tid & 63;
    int g = __builtin_amdgcn_readfirstlane(tid >> 6);
    int co0 = blockIdx.y * 64 + g * 16;
    float acc[16];
#pragma unroll
    for (int o = 0; o < 16; ++o) acc[o] = bias[co0 + o];
    for (int ci = 0; ci < CD; ++ci) {
        float x0 = xs[ci][t];
        float x1 = xs[ci][t + 1];
        float x2 = xs[ci][t + 2];
        const float4* wp = reinterpret_cast<const float4*>(wt + (size_t)(ci * CH + co0) * 4);
#pragma unroll
        for (int o = 0; o < 16; ++o) {
            float4 wv = wp[o];
            acc[o] = fmaf(wv.x, x0, fmaf(wv.y, x1, fmaf(wv.z, x2, acc[o])));
        }
    }
#pragma unroll
    for (int o = 0; o < 16; ++o)
        out[((size_t)b * CH + co0 + o) * LQ + t0 + t] = acc[o];
}

// ---------------- dt1: ConvT 128->64 k4 s2 p1, relu(in), relu(out), reg-blocked ---------
__global__ __launch_bounds__(256) void k_dt1r(const float* __restrict__ x,
                                              const float* __restrict__ w,   // [ci][64][4] native
                                              const float* __restrict__ bias,
                                              float* __restrict__ out) {
    __shared__ float xs[CH][66];
    int u0 = blockIdx.x * 64;
    int b = blockIdx.z;
    int tid = threadIdx.x;
    for (int i = tid; i < CH * 66; i += 256) {
        int ci = i / 66, j = i - ci * 66;
        int p = u0 - 1 + j;
        xs[ci][j] = (p >= 0 && p < LQ) ? fmaxf(x[((size_t)b * CH + ci) * LQ + p], 0.f) : 0.f;
    }
    __syncthreads();
    int u = tid & 63;
    int g = __builtin_amdgcn_readfirstlane(tid >> 6);
    int o0 = g * 16;
    float ae[16], ao[16];
#pragma unroll
    for (int o = 0; o < 16; ++o) { float bv = bias[o0 + o]; ae[o] = bv; ao[o] = bv; }
    for (int ci = 0; ci < CH; ++ci) {
        float xm  = xs[ci][u];
        float x0  = xs[ci][u + 1];
        float xp1 = xs[ci][u + 2];
        const float4* wp = reinterpret_cast<const float4*>(w + (size_t)(ci * CHH + o0) * 4);
#pragma unroll
        for (int o = 0; o < 16; ++o) {
            float4 wv = wp[o];
            ae[o] = fmaf(wv.y, x0, fmaf(wv.w, xm, ae[o]));
            ao[o] = fmaf(wv.x, xp1, fmaf(wv.z, x0, ao[o]));
        }
    }
    int uu = u0 + u;
#pragma unroll
    for (int o = 0; o < 16; ++o) {
        float2 r;
        r.x = fmaxf(ae[o], 0.f);
        r.y = fmaxf(ao[o], 0.f);
        reinterpret_cast<float2*>(out + ((size_t)b * CHH + o0 + o) * L1)[uu] = r;
    }
}

// ---------------- dt2: ConvT 64->1 k4 s2 p1 -> recon ----------------
__global__ __launch_bounds__(256) void k_dt2(const float* __restrict__ x,
                                             const float* __restrict__ w,
                                             const float* __restrict__ bias,
                                             float* __restrict__ out) {
    int u = blockIdx.x * 256 + threadIdx.x;       // 0..4095
    int b = blockIdx.y;
    const float* xp = x + (size_t)b * CHH * L1 + u;
    float bv = bias[0];
    float ae = bv, ao = bv;
    for (int ci = 0; ci < CHH; ++ci) {
        const float* xr = xp + ci * L1;
        float xm  = (u >= 1) ? xr[-1] : 0.f;
        float x0  = xr[0];
        float xp1 = (u < L1 - 1) ? xr[1] : 0.f;
        const float* wc = w + ci * 4;
        ae += wc[1] * x0 + wc[3] * xm;
        ao += wc[0] * xp1 + wc[2] * x0;
    }
    reinterpret_cast<float2*>(out + (size_t)b * L0)[u] = make_float2(ae, ao);
}

// ---------------- finalize: vq_loss + perplexity ----------------
__global__ __launch_bounds__(512) void k_final(const int* __restrict__ counts,
                                               const float* __restrict__ sse,
                                               float* __restrict__ out) {
    __shared__ float red[8];
    int tid = threadIdx.x;                        // 512 threads
    float p = (float)counts[tid] * (1.f / (float)NROWS);
    float v = p * logf(p + 1e-10f);
#pragma unroll
    for (int s = 32; s > 0; s >>= 1) v += __shfl_down(v, s);
    if ((tid & 63) == 0) red[tid >> 6] = v;
    __syncthreads();
    if (tid == 0) {
        float tot = 0.f;
        for (int i = 0; i < 8; ++i) tot += red[i];
        out[524288] = 1.25f * sse[0] / ((float)NROWS * (float)CD);
        out[524289] = expf(-tot);
    }
}

extern "C" void kernel_launch(void* const* d_in, const int* in_sizes, int n_in,
                              void* d_out, int out_size, void* d_ws, size_t ws_size,
                              hipStream_t stream) {
    const float* x      = (const float*)d_in[0];
    const float* ec1_w  = (const float*)d_in[1];
    const float* ec1_b  = (const float*)d_in[2];
    const float* ec2_w  = (const float*)d_in[3];
    const float* ec2_b  = (const float*)d_in[4];
    const float* ec3_w  = (const float*)d_in[5];
    const float* ec3_b  = (const float*)d_in[6];
    const float* er1_w1 = (const float*)d_in[7];
    const float* er1_w2 = (const float*)d_in[8];
    const float* er2_w1 = (const float*)d_in[9];
    const float* er2_w2 = (const float*)d_in[10];
    const float* pvq_w  = (const float*)d_in[11];
    const float* pvq_b  = (const float*)d_in[12];
    const float* cbk    = (const float*)d_in[13];
    const float* dc1_w  = (const float*)d_in[14];
    const float* dc1_b  = (const float*)d_in[15];
    const float* dr1_w1 = (const float*)d_in[16];
    const float* dr1_w2 = (const float*)d_in[17];
    const float* dr2_w1 = (const float*)d_in[18];
    const float* dr2_w2 = (const float*)d_in[19];
    const float* dt1_w  = (const float*)d_in[20];
    const float* dt1_b  = (const float*)d_in[21];
    const float* dt2_w  = (const float*)d_in[22];
    const float* dt2_b  = (const float*)d_in[23];
    float* out = (float*)d_out;

    // workspace layout: two 64MB ping-pong buffers + scalars + transposed weights
    char* ws = (char*)d_ws;
    float* A    = (float*)(ws);                        // 64 MB
    float* Bb   = (float*)(ws + 67108864);             // 64 MB
    char*  smal = ws + 134217728;
    int*   counts = (int*)smal;                        // 2048 B
    float* sse    = (float*)(smal + 2048);             // 4 B
    float* cb2    = (float*)(smal + 4096);             // 2048 B
    float* wbase  = (float*)(smal + 8192);
    float* wt_ec2 = wbase;                             // 64*128*4  = 32768
    float* wt_ec3 = wbase + 32768;                     // 128*128*4 = 65536
    float* wt_er1 = wbase + 98304;                     // 128*32*4  = 16384
    float* wt_er2 = wbase + 114688;                    // 16384
    float* wt_dc1 = wbase + 131072;                    // 64*128*4  = 32768
    float* wt_dr1 = wbase + 163840;                    // 16384
    float* wt_dr2 = wbase + 180224;                    // 16384
    float* z = Bb;                                     // 32 MB  [B,2048,64]
    float* q = Bb + 8388608;                           // 32 MB  [B,2048,64]

    hipMemsetAsync(smal, 0, 2056, stream);

    // weight transposes (tiny)
    k_wt<<<dim3((128 * 64 + 255) / 256), 256, 0, stream>>>(ec2_w, wt_ec2, 128, 64, 4);
    k_wt<<<dim3((128 * 128 + 255) / 256), 256, 0, stream>>>(ec3_w, wt_ec3, 128, 128, 3);
    k_wt<<<dim3((32 * 128 + 255) / 256), 256, 0, stream>>>(er1_w1, wt_er1, 32, 128, 3);
    k_wt<<<dim3((32 * 128 + 255) / 256), 256, 0, stream>>>(er2_w1, wt_er2, 32, 128, 3);
    k_wt<<<dim3((128 * 64 + 255) / 256), 256, 0, stream>>>(dc1_w, wt_dc1, 128, 64, 3);
    k_wt<<<dim3((32 * 128 + 255) / 256), 256, 0, stream>>>(dr1_w1, wt_dr1, 32, 128, 3);
    k_wt<<<dim3((32 * 128 + 255) / 256), 256, 0, stream>>>(dr2_w1, wt_dr2, 32, 128, 3);

    // encoder
    k_ec1<<<dim3((NB * CHH * L1) / 256), 256, 0, stream>>>(x, ec1_w, ec1_b, A);
    k_ec2r<<<dim3(LQ / 64, 2, NB), 256, 0, stream>>>(A, wt_ec2, ec2_b, Bb);
    k_conv3r<CH, CH, 64, false, true><<<dim3(LQ / 64, 2, NB), 256, 0, stream>>>(Bb, wt_ec3, ec3_b, A);
    float* HmidE = Bb;                                 // 16 MB scratch
    k_conv3r<CH, CR, 32, true, false><<<dim3(LQ / 64, 1, NB), 256, 0, stream>>>(A, wt_er1, nullptr, HmidE);
    k_resadd<<<dim3((NB * CH * LQ) / 256), 256, 0, stream>>>(HmidE, er1_w2, A);
    k_conv3r<CH, CR, 32, true, false><<<dim3(LQ / 64, 1, NB), 256, 0, stream>>>(A, wt_er2, nullptr, HmidE);
    k_resadd<<<dim3((NB * CH * LQ) / 256), 256, 0, stream>>>(HmidE, er2_w2, A);
    k_pvqr<<<dim3(LQ / 64, NB), 256, 0, stream>>>(A, pvq_w, pvq_b, z);

    // vector quantizer
    k_cb2<<<dim3(2), 256, 0, stream>>>(cbk, cb2);
    k_vq<<<dim3(NROWS / 512), 256, 0, stream>>>(z, cbk, cb2, q, counts, sse);

    // decoder
    k_dc1r<<<dim3(LQ / 64, 2, NB), 256, 0, stream>>>(q, wt_dc1, dc1_b, A);
    float* HmidD = Bb;                                 // z dead; q consumed by dc1
    k_conv3r<CH, CR, 32, true, false><<<dim3(LQ / 64, 1, NB), 256, 0, stream>>>(A, wt_dr1, nullptr, HmidD);
    k_resadd<<<dim3((NB * CH * LQ) / 256), 256, 0, stream>>>(HmidD, dr1_w2, A);
    k_conv3r<CH, CR, 32, true, false><<<dim3(LQ / 64, 1, NB), 256, 0, stream>>>(A, wt_dr2, nullptr, HmidD);
    k_resadd<<<dim3((NB * CH * LQ) / 256), 256, 0, stream>>>(HmidD, dr2_w2, A);
    k_dt1r<<<dim3(LQ / 64, 1, NB), 256, 0, stream>>>(A, dt1_w, dt1_b, Bb);
    k_dt2<<<dim3(L1 / 256, NB), 256, 0, stream>>>(Bb, dt2_w, dt2_b, out);

    // scalars
    k_final<<<dim3(1), 512, 0, stream>>>(counts, sse, out);
}

// Round 3
// 1419.923 us; speedup vs baseline: 3.7059x; 1.4246x over previous
//
#include <hip/hip_runtime.h>
#include <math.h>

// Problem constants
static constexpr int NB  = 64;     // batch
static constexpr int L0  = 8192;   // input length
static constexpr int L1  = 4096;   // after ec1
static constexpr int LQ  = 2048;   // latent length
static constexpr int CH  = 128;    // hidden H
static constexpr int CHH = 64;     // H/2
static constexpr int CR  = 32;     // residual hidden
static constexpr int CD  = 64;     // codebook dim D
static constexpr int NK  = 512;    // codebook size K
static constexpr int NROWS = NB * LQ;  // 131072 latent vectors

using short8 = __attribute__((ext_vector_type(8))) short;
using f32x4  = __attribute__((ext_vector_type(4))) float;

union BU { unsigned int u[4]; short8 v; };

__device__ inline f32x4 mfma16(short8 a, short8 b, f32x4 c) {
    return __builtin_amdgcn_mfma_f32_16x16x32_bf16(a, b, c, 0, 0, 0);
}

// ---- weight->fragment prep: dst frag order [tap][cb][kb][cl*32+hi*8+j] bf16 ----
// value = src[co][ci][tap] (iok=0, OIK) or src[ci][co][tap] (iok=1, IOK)
__global__ __launch_bounds__(256) void k_wtf(const float* __restrict__ src,
                                             short* __restrict__ dst,
                                             int CO, int CI, int K, int iok) {
    int i = blockIdx.x * 256 + threadIdx.x;
    int total = K * CO * CI;
    if (i >= total) return;
    int j  = i & 7;
    int hi = (i >> 3) & 3;
    int cl = (i >> 5) & 15;
    int rest = i >> 9;
    int CIb = CI >> 5, COb = CO >> 4;
    int kb = rest % CIb; rest /= CIb;
    int cb = rest % COb;
    int tap = rest / COb;
    int co = cb * 16 + cl, ci = kb * 32 + hi * 8 + j;
    float v = iok ? src[(ci * CO + co) * K + tap] : src[(co * CI + ci) * K + tap];
    unsigned int bb = __builtin_bit_cast(unsigned int, v);
    unsigned int r = (bb + 0x7FFFu + ((bb >> 16) & 1u)) >> 16;
    dst[i] = (short)r;
}

// ---------------- ec1: [B,1,8192] -> [B,64,4096], k4 s2 p1, bias+ReLU ----------------
__global__ __launch_bounds__(256) void k_ec1(const float* __restrict__ x,
                                             const float* __restrict__ w,
                                             const float* __restrict__ bias,
                                             float* __restrict__ out) {
    int n = blockIdx.x * 256 + threadIdx.x;
    int t  = n & (L1 - 1);
    int co = (n >> 12) & (CHH - 1);
    int b  = n >> 18;
    const float* xp = x + b * L0;
    float acc = bias[co];
    int p0 = 2 * t - 1;
#pragma unroll
    for (int k = 0; k < 4; ++k) {
        int p = p0 + k;
        if (p >= 0 && p < L0) acc += w[co * 4 + k] * xp[p];
    }
    out[n] = fmaxf(acc, 0.f);
}

// ---------------- MFMA tap-decomposed conv template ----------------
// out[b][co][t0+t] = bias[co] + sum_tap sum_ci W[co][ci][tap] * x[ci][(t0+t)*S - 1 + tap]
template <int CIN, int COUT, int NTAPS, int TSTRIDE, int LIN, bool RELU_IN,
          bool TRANS_IN, bool HAS_BIAS, bool RELU_OUT>
__global__ __launch_bounds__(256) void k_mfconv(const float* __restrict__ x,
                                                const short* __restrict__ wf,
                                                const float* __restrict__ bias,
                                                float* __restrict__ out) {
    constexpr int XW = 63 * TSTRIDE + NTAPS;
    constexpr int MR = (COUT == 128) ? 4 : 1;
    constexpr int COb = COUT / 16, CIb = CIN / 32;
    __shared__ float xs[CIN][XW];
    int t0 = blockIdx.x * 64;
    int b  = blockIdx.z;
    int tid = threadIdx.x;

    if (TRANS_IN) {
        for (int i = tid; i < CIN * XW; i += 256) {
            int ci = i & (CIN - 1), j = i / CIN;
            int p = t0 - 1 + j;
            float v = (p >= 0 && p < LIN) ? x[((size_t)b * LIN + p) * CIN + ci] : 0.f;
            if (RELU_IN) v = fmaxf(v, 0.f);
            xs[ci][j] = v;
        }
    } else {
        for (int i = tid; i < CIN * XW; i += 256) {
            int ci = i / XW, j = i - ci * XW;
            int p = t0 * TSTRIDE - 1 + j;
            float v = (p >= 0 && p < LIN) ? x[((size_t)b * CIN + ci) * LIN + p] : 0.f;
            if (RELU_IN) v = fmaxf(v, 0.f);
            xs[ci][j] = v;
        }
    }
    __syncthreads();

    int l  = tid & 63;
    int w  = tid >> 6;
    int cl = l & 15, hi = l >> 4;
    int co_w = (w & 1) * MR * 16;
    int t_w  = (w >> 1) * 32;

    f32x4 acc[MR][2];
#pragma unroll
    for (int m = 0; m < MR; ++m)
#pragma unroll
        for (int n = 0; n < 2; ++n) acc[m][n] = (f32x4){0.f, 0.f, 0.f, 0.f};

#pragma unroll
    for (int tap = 0; tap < NTAPS; ++tap) {
#pragma unroll
        for (int kb = 0; kb < CIb; ++kb) {
            const short* ap = wf + (size_t)((tap * COb + co_w / 16) * CIb + kb) * 512
                            + cl * 32 + hi * 8;
            short8 a[MR];
#pragma unroll
            for (int m = 0; m < MR; ++m)
                a[m] = *reinterpret_cast<const short8*>(ap + (size_t)m * CIb * 512);
            int ci0 = kb * 32 + hi * 8;
            short8 bf[2];
#pragma unroll
            for (int n = 0; n < 2; ++n) {
                int xc = (t_w + n * 16 + cl) * TSTRIDE + tap;
                const float* ptr = &xs[ci0][xc];
                BU bu;
#pragma unroll
                for (int p = 0; p < 4; ++p) {
                    unsigned int u0 = __builtin_bit_cast(unsigned int, ptr[(2 * p) * XW]);
                    unsigned int u1 = __builtin_bit_cast(unsigned int, ptr[(2 * p + 1) * XW]);
                    bu.u[p] = (u0 >> 16) | (u1 & 0xFFFF0000u);
                }
                bf[n] = bu.v;
            }
#pragma unroll
            for (int m = 0; m < MR; ++m)
#pragma unroll
                for (int n = 0; n < 2; ++n)
                    acc[m][n] = mfma16(a[m], bf[n], acc[m][n]);
        }
    }

#pragma unroll
    for (int m = 0; m < MR; ++m) {
#pragma unroll
        for (int n = 0; n < 2; ++n) {
#pragma unroll
            for (int r = 0; r < 4; ++r) {
                int co = co_w + m * 16 + hi * 4 + r;
                int t  = t0 + t_w + n * 16 + cl;
                float v = acc[m][n][r];
                if (HAS_BIAS) v += bias[co];
                if (RELU_OUT) v = fmaxf(v, 0.f);
                out[((size_t)b * COUT + co) * LQ + t] = v;
            }
        }
    }
}

// ---------------- dt1 MFMA: ConvT 128->64 k4 s2 p1, relu(in), relu(out) ----------------
__global__ __launch_bounds__(256) void k_dt1m(const float* __restrict__ x,
                                              const short* __restrict__ wf,  // IOK frags
                                              const float* __restrict__ bias,
                                              float* __restrict__ out) {
    __shared__ float xs[CH][66];
    int t0 = blockIdx.x * 64;     // u-range base
    int b  = blockIdx.z;
    int tid = threadIdx.x;
    for (int i = tid; i < CH * 66; i += 256) {
        int ci = i / 66, j = i - ci * 66;
        int p = t0 - 1 + j;
        xs[ci][j] = (p >= 0 && p < LQ) ? fmaxf(x[((size_t)b * CH + ci) * LQ + p], 0.f) : 0.f;
    }
    __syncthreads();

    int l  = tid & 63;
    int w  = tid >> 6;
    int cl = l & 15, hi = l >> 4;
    int co_w = (w & 1) * 32;
    int u_w  = (w >> 1) * 32;

    f32x4 ae[2][2], ao[2][2];
#pragma unroll
    for (int m = 0; m < 2; ++m)
#pragma unroll
        for (int n = 0; n < 2; ++n) {
            ae[m][n] = (f32x4){0.f, 0.f, 0.f, 0.f};
            ao[m][n] = (f32x4){0.f, 0.f, 0.f, 0.f};
        }

    const int TK[4] = {1, 3, 0, 2};
    const int TO[4] = {1, 0, 2, 1};
#pragma unroll
    for (int te = 0; te < 4; ++te) {
        int k = TK[te], off = TO[te];
#pragma unroll
        for (int kb = 0; kb < 4; ++kb) {
            const short* ap = wf + (size_t)((k * 4 + co_w / 16) * 4 + kb) * 512
                            + cl * 32 + hi * 8;
            short8 a[2];
#pragma unroll
            for (int m = 0; m < 2; ++m)
                a[m] = *reinterpret_cast<const short8*>(ap + (size_t)m * 4 * 512);
            int ci0 = kb * 32 + hi * 8;
            short8 bf[2];
#pragma unroll
            for (int n = 0; n < 2; ++n) {
                int xc = u_w + n * 16 + cl + off;
                const float* ptr = &xs[ci0][xc];
                BU bu;
#pragma unroll
                for (int p = 0; p < 4; ++p) {
                    unsigned int u0 = __builtin_bit_cast(unsigned int, ptr[(2 * p) * 66]);
                    unsigned int u1 = __builtin_bit_cast(unsigned int, ptr[(2 * p + 1) * 66]);
                    bu.u[p] = (u0 >> 16) | (u1 & 0xFFFF0000u);
                }
                bf[n] = bu.v;
            }
#pragma unroll
            for (int m = 0; m < 2; ++m)
#pragma unroll
                for (int n = 0; n < 2; ++n) {
                    if (te < 2) ae[m][n] = mfma16(a[m], bf[n], ae[m][n]);
                    else        ao[m][n] = mfma16(a[m], bf[n], ao[m][n]);
                }
        }
    }

#pragma unroll
    for (int m = 0; m < 2; ++m) {
#pragma unroll
        for (int n = 0; n < 2; ++n) {
#pragma unroll
            for (int r = 0; r < 4; ++r) {
                int co = co_w + m * 16 + hi * 4 + r;
                int u  = t0 + u_w + n * 16 + cl;
                float bv = bias[co];
                float2 rr;
                rr.x = fmaxf(ae[m][n][r] + bv, 0.f);
                rr.y = fmaxf(ao[m][n][r] + bv, 0.f);
                *reinterpret_cast<float2*>(&out[((size_t)b * CHH + co) * L1 + 2 * u]) = rr;
            }
        }
    }
}

// ---------------- residual second conv: x += W2 @ relu(h), k=1, 32->128 ----------------
__global__ __launch_bounds__(256) void k_resadd(const float* __restrict__ h,
                                                const float* __restrict__ w2,
                                                float* __restrict__ x) {
    int n = blockIdx.x * 256 + threadIdx.x;
    int t  = n & (LQ - 1);
    int co = (n >> 11) & (CH - 1);
    int b  = n >> 18;
    const float* hp = h + b * CR * LQ + t;
    const float* wp = w2 + co * CR;
    float acc = 0.f;
#pragma unroll
    for (int ci = 0; ci < CR; ++ci)
        acc += wp[ci] * fmaxf(hp[ci * LQ], 0.f);
    x[n] += acc;
}

// ---------------- pvq: z[b,t,d] = bias[d] + sum_ci w[d,ci]*relu(x[b,ci,t]) ----------------
__global__ __launch_bounds__(256) void k_pvqr(const float* __restrict__ x,
                                              const float* __restrict__ w,
                                              const float* __restrict__ bias,
                                              float* __restrict__ z) {
    __shared__ float xs[CH][64];
    __shared__ float wT[CH][64];
    int tid = threadIdx.x;
    int t0 = blockIdx.x * 64;
    int b = blockIdx.y;
    for (int i = tid; i < CD * CH; i += 256) {
        int d = i >> 7, ci = i & 127;
        wT[ci][d] = w[i];
    }
    for (int i = tid; i < CH * 64; i += 256) {
        int ci = i >> 6, j = i & 63;
        xs[ci][j] = fmaxf(x[((size_t)b * CH + ci) * LQ + t0 + j], 0.f);
    }
    __syncthreads();
    int d = tid & 63;
    int tg = tid >> 6;
    float bv = bias[d];
    float acc[16];
#pragma unroll
    for (int i = 0; i < 16; ++i) acc[i] = bv;
    for (int ci = 0; ci < CH; ++ci) {
        float wv = wT[ci][d];
        const float4* xr = reinterpret_cast<const float4*>(&xs[ci][tg * 16]);
        float4 a = xr[0], bq = xr[1], c = xr[2], e = xr[3];
        acc[0]  = fmaf(wv, a.x, acc[0]);
        acc[1]  = fmaf(wv, a.y, acc[1]);
        acc[2]  = fmaf(wv, a.z, acc[2]);
        acc[3]  = fmaf(wv, a.w, acc[3]);
        acc[4]  = fmaf(wv, bq.x, acc[4]);
        acc[5]  = fmaf(wv, bq.y, acc[5]);
        acc[6]  = fmaf(wv, bq.z, acc[6]);
        acc[7]  = fmaf(wv, bq.w, acc[7]);
        acc[8]  = fmaf(wv, c.x, acc[8]);
        acc[9]  = fmaf(wv, c.y, acc[9]);
        acc[10] = fmaf(wv, c.z, acc[10]);
        acc[11] = fmaf(wv, c.w, acc[11]);
        acc[12] = fmaf(wv, e.x, acc[12]);
        acc[13] = fmaf(wv, e.y, acc[13]);
        acc[14] = fmaf(wv, e.z, acc[14]);
        acc[15] = fmaf(wv, e.w, acc[15]);
    }
    int tbase = t0 + tg * 16;
#pragma unroll
    for (int i = 0; i < 16; ++i)
        z[((size_t)b * LQ + tbase + i) * CD + d] = acc[i];
}

// ---------------- cb2[k] = |codebook_k|^2 ----------------
__global__ __launch_bounds__(256) void k_cb2(const float* __restrict__ cb,
                                             float* __restrict__ cb2) {
    int k = blockIdx.x * 256 + threadIdx.x;
    if (k >= NK) return;
    const float* r = cb + k * CD;
    float s = 0.f;
#pragma unroll 8
    for (int i = 0; i < CD; ++i) s += r[i] * r[i];
    cb2[k] = s;
}

// ---------------- VQ: argmin + q gather + sse + histogram ----------------
__global__ __launch_bounds__(256) void k_vq(const float* __restrict__ z,
                                            const float* __restrict__ cb,
                                            const float* __restrict__ cb2,
                                            float* __restrict__ q,
                                            int* __restrict__ counts,
                                            float* __restrict__ sse) {
    __shared__ float cs[128][64];
    __shared__ int hist[NK];
    __shared__ float red[256];
    int tid = threadIdx.x;
    int row0 = blockIdx.x * 512 + tid;
    float4 za[16], zb[16];
    const float4* zr0 = reinterpret_cast<const float4*>(z + (size_t)row0 * CD);
    const float4* zr1 = reinterpret_cast<const float4*>(z + (size_t)(row0 + 256) * CD);
#pragma unroll
    for (int i = 0; i < 16; ++i) { za[i] = zr0[i]; zb[i] = zr1[i]; }
    for (int i = tid; i < NK; i += 256) hist[i] = 0;
    float bestA = 1e30f, bestB = 1e30f;
    int idxA = 0, idxB = 0;
    for (int c0 = 0; c0 < NK; c0 += 128) {
        __syncthreads();
        const float4* src = reinterpret_cast<const float4*>(cb + c0 * CD);
        float4* dst = reinterpret_cast<float4*>(&cs[0][0]);
        for (int i = tid; i < 128 * 64 / 4; i += 256) dst[i] = src[i];
        __syncthreads();
        for (int c = 0; c < 128; ++c) {
            const float4* cr = reinterpret_cast<const float4*>(&cs[c][0]);
            float dA = 0.f, dB = 0.f;
#pragma unroll
            for (int i = 0; i < 16; ++i) {
                float4 cv = cr[i];
                dA += cv.x * za[i].x + cv.y * za[i].y + cv.z * za[i].z + cv.w * za[i].w;
                dB += cv.x * zb[i].x + cv.y * zb[i].y + cv.z * zb[i].z + cv.w * zb[i].w;
            }
            float c2 = cb2[c0 + c];
            float sA = c2 - 2.f * dA;
            float sB = c2 - 2.f * dB;
            if (sA < bestA) { bestA = sA; idxA = c0 + c; }
            if (sB < bestB) { bestB = sB; idxB = c0 + c; }
        }
    }
    float err = 0.f;
    {
        const float4* qa = reinterpret_cast<const float4*>(cb + idxA * CD);
        float4* qo = reinterpret_cast<float4*>(q + (size_t)row0 * CD);
#pragma unroll
        for (int i = 0; i < 16; ++i) {
            float4 cv = qa[i]; qo[i] = cv;
            float dx = cv.x - za[i].x, dy = cv.y - za[i].y;
            float dz2 = cv.z - za[i].z, dw = cv.w - za[i].w;
            err += dx * dx + dy * dy + dz2 * dz2 + dw * dw;
        }
        const float4* qb = reinterpret_cast<const float4*>(cb + idxB * CD);
        float4* qo1 = reinterpret_cast<float4*>(q + (size_t)(row0 + 256) * CD);
#pragma unroll
        for (int i = 0; i < 16; ++i) {
            float4 cv = qb[i]; qo1[i] = cv;
            float dx = cv.x - zb[i].x, dy = cv.y - zb[i].y;
            float dz2 = cv.z - zb[i].z, dw = cv.w - zb[i].w;
            err += dx * dx + dy * dy + dz2 * dz2 + dw * dw;
        }
    }
    atomicAdd(&hist[idxA], 1);
    atomicAdd(&hist[idxB], 1);
    red[tid] = err;
    __syncthreads();
    for (int s = 128; s > 0; s >>= 1) {
        if (tid < s) red[tid] += red[tid + s];
        __syncthreads();
    }
    if (tid == 0) atomicAdd(sse, red[0]);
    for (int i = tid; i < NK; i += 256) atomicAdd(&counts[i], hist[i]);
}

// ---------------- dt2: ConvT 64->1 k4 s2 p1 -> recon ----------------
__global__ __launch_bounds__(256) void k_dt2(const float* __restrict__ x,
                                             const float* __restrict__ w,
                                             const float* __restrict__ bias,
                                             float* __restrict__ out) {
    int u = blockIdx.x * 256 + threadIdx.x;
    int b = blockIdx.y;
    const float* xp = x + (size_t)b * CHH * L1 + u;
    float bv = bias[0];
    float ae = bv, ao = bv;
    for (int ci = 0; ci < CHH; ++ci) {
        const float* xr = xp + ci * L1;
        float xm  = (u >= 1) ? xr[-1] : 0.f;
        float x0  = xr[0];
        float xp1 = (u < L1 - 1) ? xr[1] : 0.f;
        const float* wc = w + ci * 4;
        ae += wc[1] * x0 + wc[3] * xm;
        ao += wc[0] * xp1 + wc[2] * x0;
    }
    reinterpret_cast<float2*>(out + (size_t)b * L0)[u] = make_float2(ae, ao);
}

// ---------------- finalize: vq_loss + perplexity ----------------
__global__ __launch_bounds__(512) void k_final(const int* __restrict__ counts,
                                               const float* __restrict__ sse,
                                               float* __restrict__ out) {
    __shared__ float red[8];
    int tid = threadIdx.x;
    float p = (float)counts[tid] * (1.f / (float)NROWS);
    float v = p * logf(p + 1e-10f);
#pragma unroll
    for (int s = 32; s > 0; s >>= 1) v += __shfl_down(v, s);
    if ((tid & 63) == 0) red[tid >> 6] = v;
    __syncthreads();
    if (tid == 0) {
        float tot = 0.f;
        for (int i = 0; i < 8; ++i) tot += red[i];
        out[524288] = 1.25f * sse[0] / ((float)NROWS * (float)CD);
        out[524289] = expf(-tot);
    }
}

extern "C" void kernel_launch(void* const* d_in, const int* in_sizes, int n_in,
                              void* d_out, int out_size, void* d_ws, size_t ws_size,
                              hipStream_t stream) {
    const float* x      = (const float*)d_in[0];
    const float* ec1_w  = (const float*)d_in[1];
    const float* ec1_b  = (const float*)d_in[2];
    const float* ec2_w  = (const float*)d_in[3];
    const float* ec2_b  = (const float*)d_in[4];
    const float* ec3_w  = (const float*)d_in[5];
    const float* ec3_b  = (const float*)d_in[6];
    const float* er1_w1 = (const float*)d_in[7];
    const float* er1_w2 = (const float*)d_in[8];
    const float* er2_w1 = (const float*)d_in[9];
    const float* er2_w2 = (const float*)d_in[10];
    const float* pvq_w  = (const float*)d_in[11];
    const float* pvq_b  = (const float*)d_in[12];
    const float* cbk    = (const float*)d_in[13];
    const float* dc1_w  = (const float*)d_in[14];
    const float* dc1_b  = (const float*)d_in[15];
    const float* dr1_w1 = (const float*)d_in[16];
    const float* dr1_w2 = (const float*)d_in[17];
    const float* dr2_w1 = (const float*)d_in[18];
    const float* dr2_w2 = (const float*)d_in[19];
    const float* dt1_w  = (const float*)d_in[20];
    const float* dt1_b  = (const float*)d_in[21];
    const float* dt2_w  = (const float*)d_in[22];
    const float* dt2_b  = (const float*)d_in[23];
    float* out = (float*)d_out;

    char* ws = (char*)d_ws;
    float* A    = (float*)(ws);                        // 64 MB
    float* Bb   = (float*)(ws + 67108864);             // 64 MB
    char*  smal = ws + 134217728;
    int*   counts = (int*)smal;                        // 2048 B
    float* sse    = (float*)(smal + 2048);             // 4 B
    float* cb2    = (float*)(smal + 4096);             // 2048 B
    // bf16 fragment-ordered weights
    short* wf_ec2 = (short*)(smal + 8192);             // 32768 sh
    short* wf_ec3 = wf_ec2 + 32768;                    // 49152 sh
    short* wf_er1 = wf_ec3 + 49152;                    // 12288 sh
    short* wf_er2 = wf_er1 + 12288;
    short* wf_dc1 = wf_er2 + 12288;                    // 24576 sh
    short* wf_dr1 = wf_dc1 + 24576;
    short* wf_dr2 = wf_dr1 + 12288;
    short* wf_dt1 = wf_dr2 + 12288;                    // 32768 sh
    float* z = Bb;                                     // 32 MB  [B,2048,64]
    float* q = Bb + 8388608;                           // 32 MB  [B,2048,64]

    hipMemsetAsync(smal, 0, 2056, stream);

    // weight fragment prep (tiny)
    k_wtf<<<dim3(128), 256, 0, stream>>>(ec2_w, wf_ec2, 128, 64, 4, 0);
    k_wtf<<<dim3(192), 256, 0, stream>>>(ec3_w, wf_ec3, 128, 128, 3, 0);
    k_wtf<<<dim3(48), 256, 0, stream>>>(er1_w1, wf_er1, 32, 128, 3, 0);
    k_wtf<<<dim3(48), 256, 0, stream>>>(er2_w1, wf_er2, 32, 128, 3, 0);
    k_wtf<<<dim3(96), 256, 0, stream>>>(dc1_w, wf_dc1, 128, 64, 3, 0);
    k_wtf<<<dim3(48), 256, 0, stream>>>(dr1_w1, wf_dr1, 32, 128, 3, 0);
    k_wtf<<<dim3(48), 256, 0, stream>>>(dr2_w1, wf_dr2, 32, 128, 3, 0);
    k_wtf<<<dim3(128), 256, 0, stream>>>(dt1_w, wf_dt1, 64, 128, 4, 1);

    // encoder
    k_ec1<<<dim3((NB * CHH * L1) / 256), 256, 0, stream>>>(x, ec1_w, ec1_b, A);
    k_mfconv<64, 128, 4, 2, L1, false, false, true, true>
        <<<dim3(LQ / 64, 1, NB), 256, 0, stream>>>(A, wf_ec2, ec2_b, Bb);
    k_mfconv<128, 128, 3, 1, LQ, false, false, true, false>
        <<<dim3(LQ / 64, 1, NB), 256, 0, stream>>>(Bb, wf_ec3, ec3_b, A);
    float* HmidE = Bb;
    k_mfconv<128, 32, 3, 1, LQ, true, false, false, false>
        <<<dim3(LQ / 64, 1, NB), 256, 0, stream>>>(A, wf_er1, nullptr, HmidE);
    k_resadd<<<dim3((NB * CH * LQ) / 256), 256, 0, stream>>>(HmidE, er1_w2, A);
    k_mfconv<128, 32, 3, 1, LQ, true, false, false, false>
        <<<dim3(LQ / 64, 1, NB), 256, 0, stream>>>(A, wf_er2, nullptr, HmidE);
    k_resadd<<<dim3((NB * CH * LQ) / 256), 256, 0, stream>>>(HmidE, er2_w2, A);
    k_pvqr<<<dim3(LQ / 64, NB), 256, 0, stream>>>(A, pvq_w, pvq_b, z);

    // vector quantizer
    k_cb2<<<dim3(2), 256, 0, stream>>>(cbk, cb2);
    k_vq<<<dim3(NROWS / 512), 256, 0, stream>>>(z, cbk, cb2, q, counts, sse);

    // decoder
    k_mfconv<64, 128, 3, 1, LQ, false, true, true, false>
        <<<dim3(LQ / 64, 1, NB), 256, 0, stream>>>(q, wf_dc1, dc1_b, A);
    float* HmidD = Bb;
    k_mfconv<128, 32, 3, 1, LQ, true, false, false, false>
        <<<dim3(LQ / 64, 1, NB), 256, 0, stream>>>(A, wf_dr1, nullptr, HmidD);
    k_resadd<<<dim3((NB * CH * LQ) / 256), 256, 0, stream>>>(HmidD, dr1_w2, A);
    k_mfconv<128, 32, 3, 1, LQ, true, false, false, false>
        <<<dim3(LQ / 64, 1, NB), 256, 0, stream>>>(A, wf_dr2, nullptr, HmidD);
    k_resadd<<<dim3((NB * CH * LQ) / 256), 256, 0, stream>>>(HmidD, dr2_w2, A);
    k_dt1m<<<dim3(LQ / 64, 1, NB), 256, 0, stream>>>(A, wf_dt1, dt1_b, Bb);
    k_dt2<<<dim3(L1 / 256, NB), 256, 0, stream>>>(Bb, dt2_w, dt2_b, out);

    // scalars
    k_final<<<dim3(1), 512, 0, stream>>>(counts, sse, out);
}

// Round 6
// 1104.504 us; speedup vs baseline: 4.7642x; 1.2856x over previous
//
#include <hip/hip_runtime.h>
#include <math.h>

// Problem constants
static constexpr int NB  = 64;     // batch
static constexpr int L0  = 8192;   // input length
static constexpr int L1  = 4096;   // after ec1
static constexpr int LQ  = 2048;   // latent length
static constexpr int CH  = 128;    // hidden H
static constexpr int CHH = 64;     // H/2
static constexpr int CR  = 32;     // residual hidden
static constexpr int CD  = 64;     // codebook dim D
static constexpr int NK  = 512;    // codebook size K
static constexpr int NROWS = NB * LQ;  // 131072 latent vectors

using short8 = __attribute__((ext_vector_type(8))) short;
using f32x4  = __attribute__((ext_vector_type(4))) float;

__device__ inline f32x4 mfma16(short8 a, short8 b, f32x4 c) {
    return __builtin_amdgcn_mfma_f32_16x16x32_bf16(a, b, c, 0, 0, 0);
}

__device__ inline unsigned short bf16rne(float v) {
    unsigned int bb = __builtin_bit_cast(unsigned int, v);
    unsigned int r = (bb + 0x7FFFu + ((bb >> 16) & 1u)) >> 16;
    return (unsigned short)r;
}
__device__ inline float bf2f(unsigned short s) {
    unsigned int u = ((unsigned int)s) << 16;
    return __builtin_bit_cast(float, u);
}

// ---- conv weight->fragment prep: dst [tap][cb][kb][cl*32+hi*8+j] bf16 ----
__global__ __launch_bounds__(256) void k_wtf(const float* __restrict__ src,
                                             short* __restrict__ dst,
                                             int CO, int CI, int K, int iok) {
    int i = blockIdx.x * 256 + threadIdx.x;
    int total = K * CO * CI;
    if (i >= total) return;
    int j  = i & 7;
    int hi = (i >> 3) & 3;
    int cl = (i >> 5) & 15;
    int rest = i >> 9;
    int CIb = CI >> 5, COb = CO >> 4;
    int kb = rest % CIb; rest /= CIb;
    int cb = rest % COb;
    int tap = rest / COb;
    int co = cb * 16 + cl, ci = kb * 32 + hi * 8 + j;
    float v = iok ? src[(ci * CO + co) * K + tap] : src[(co * CI + ci) * K + tap];
    dst[i] = (short)bf16rne(v);
}

// ---- codebook A-frag prep, split precision: -2*cb = hi + lo (both bf16) ----
// layout: [(mt*2+half)*64 + l]*8 + j
__global__ __launch_bounds__(256) void k_cbf(const float* __restrict__ cb,
                                             short* __restrict__ hi_dst,
                                             short* __restrict__ lo_dst) {
    int i = blockIdx.x * 256 + threadIdx.x;   // 32768
    if (i >= NK * CD) return;
    int j    = i & 7;
    int l    = (i >> 3) & 63;
    int half = (i >> 9) & 1;
    int mt   = i >> 10;
    int cl = l & 15, hi = l >> 4;
    int m = mt * 16 + cl;
    int k = half * 32 + hi * 8 + j;
    float v = -2.f * cb[m * CD + k];
    unsigned short h = bf16rne(v);
    float r = v - bf2f(h);                 // exact in fp32
    hi_dst[i] = (short)h;
    lo_dst[i] = (short)bf16rne(r);
}

// ---------------- ec1: [B,1,8192] -> [B,64,4096], k4 s2 p1, bias+ReLU ----------------
__global__ __launch_bounds__(256) void k_ec1(const float* __restrict__ x,
                                             const float* __restrict__ w,
                                             const float* __restrict__ bias,
                                             float* __restrict__ out) {
    int n = blockIdx.x * 256 + threadIdx.x;
    int t  = n & (L1 - 1);
    int co = (n >> 12) & (CHH - 1);
    int b  = n >> 18;
    const float* xp = x + b * L0;
    float acc = bias[co];
    int p0 = 2 * t - 1;
#pragma unroll
    for (int k = 0; k < 4; ++k) {
        int p = p0 + k;
        if (p >= 0 && p < L0) acc += w[co * 4 + k] * xp[p];
    }
    out[n] = fmaxf(acc, 0.f);
}

// ---------------- MFMA conv v2: bf16 swizzled LDS [t][ci], ds_read_b128 B-frags -------
template <int CIN, int COUT, int NTAPS, int TSTRIDE, int SWS, int LIN,
          bool RELU_IN, bool TRANS_IN, bool HAS_BIAS, bool RELU_OUT>
__global__ __launch_bounds__(256) void k_mfconv2(const float* __restrict__ x,
                                                 const short* __restrict__ wf,
                                                 const float* __restrict__ bias,
                                                 float* __restrict__ out) {
    constexpr int XW = 63 * TSTRIDE + NTAPS;
    constexpr int MR = (COUT == 128) ? 4 : 1;
    constexpr int COb = COUT / 16, CIb = CIN / 32;
    __shared__ unsigned int xsu[CIN * XW / 2];
    int t0 = blockIdx.x * 64;
    int b  = blockIdx.z;
    int tid = threadIdx.x;

    if (TRANS_IN) {
        for (int i = tid; i < XW * (CIN / 2); i += 256) {
            int j = i / (CIN / 2);
            int ci = (i - j * (CIN / 2)) * 2;
            int p = t0 - 1 + j;
            float vx = 0.f, vy = 0.f;
            if (p >= 0 && p < LIN) {
                const float* s = x + ((size_t)b * LIN + p) * CIN + ci;
                vx = s[0]; vy = s[1];
            }
            if (RELU_IN) { vx = fmaxf(vx, 0.f); vy = fmaxf(vy, 0.f); }
            unsigned int u = (__builtin_bit_cast(unsigned int, vx) >> 16)
                           | (__builtin_bit_cast(unsigned int, vy) & 0xFFFF0000u);
            int byte = (j * CIN + ci) * 2;
            byte ^= ((j >> SWS) & 7) << 4;
            xsu[byte >> 2] = u;
        }
    } else {
        for (int i = tid; i < (CIN / 2) * XW; i += 256) {
            int ci2 = i / XW;
            int j = i - ci2 * XW;
            int ci = ci2 * 2;
            int p = t0 * TSTRIDE - 1 + j;
            float vx = 0.f, vy = 0.f;
            if (p >= 0 && p < LIN) {
                const float* s = x + ((size_t)b * CIN + ci) * LIN + p;
                vx = s[0]; vy = s[LIN];
            }
            if (RELU_IN) { vx = fmaxf(vx, 0.f); vy = fmaxf(vy, 0.f); }
            unsigned int u = (__builtin_bit_cast(unsigned int, vx) >> 16)
                           | (__builtin_bit_cast(unsigned int, vy) & 0xFFFF0000u);
            int byte = (j * CIN + ci) * 2;
            byte ^= ((j >> SWS) & 7) << 4;
            xsu[byte >> 2] = u;
        }
    }
    __syncthreads();

    int l  = tid & 63;
    int w  = tid >> 6;
    int cl = l & 15, hi = l >> 4;
    int co_w = (w & 1) * (MR * 16);
    int t_w  = (w >> 1) * 32;

    f32x4 acc[MR][2];
#pragma unroll
    for (int m = 0; m < MR; ++m)
#pragma unroll
        for (int n = 0; n < 2; ++n) acc[m][n] = (f32x4){0.f, 0.f, 0.f, 0.f};

#pragma unroll
    for (int tap = 0; tap < NTAPS; ++tap) {
#pragma unroll
        for (int kb = 0; kb < CIb; ++kb) {
            const short* ap = wf + ((size_t)((tap * COb + co_w / 16) * CIb + kb)) * 512
                            + cl * 32 + hi * 8;
            short8 a[MR];
#pragma unroll
            for (int m = 0; m < MR; ++m)
                a[m] = *reinterpret_cast<const short8*>(ap + (size_t)m * CIb * 512);
            short8 bf[2];
#pragma unroll
            for (int n = 0; n < 2; ++n) {
                int tt = (t_w + n * 16 + cl) * TSTRIDE + tap;
                int byte = (tt * CIN + kb * 32 + hi * 8) * 2;
                byte ^= ((tt >> SWS) & 7) << 4;
                bf[n] = *reinterpret_cast<const short8*>(
                            reinterpret_cast<const char*>(xsu) + byte);
            }
#pragma unroll
            for (int m = 0; m < MR; ++m)
#pragma unroll
                for (int n = 0; n < 2; ++n)
                    acc[m][n] = mfma16(a[m], bf[n], acc[m][n]);
        }
    }

#pragma unroll
    for (int m = 0; m < MR; ++m) {
#pragma unroll
        for (int n = 0; n < 2; ++n) {
#pragma unroll
            for (int r = 0; r < 4; ++r) {
                int co = co_w + m * 16 + hi * 4 + r;
                int t  = t0 + t_w + n * 16 + cl;
                float v = acc[m][n][r];
                if (HAS_BIAS) v += bias[co];
                if (RELU_OUT) v = fmaxf(v, 0.f);
                out[((size_t)b * COUT + co) * LQ + t] = v;
            }
        }
    }
}

// ---------------- dt1 MFMA v2: ConvT 128->64 k4 s2 p1, relu(in), relu(out) -------------
__global__ __launch_bounds__(256) void k_dt1m(const float* __restrict__ x,
                                              const short* __restrict__ wf,  // IOK frags
                                              const float* __restrict__ bias,
                                              float* __restrict__ out) {
    constexpr int XW = 66;
    __shared__ unsigned int xsu[CH * XW / 2];
    int t0 = blockIdx.x * 64;     // u-range base
    int b  = blockIdx.z;
    int tid = threadIdx.x;
    for (int i = tid; i < (CH / 2) * XW; i += 256) {
        int ci2 = i / XW;
        int j = i - ci2 * XW;
        int ci = ci2 * 2;
        int p = t0 - 1 + j;
        float vx = 0.f, vy = 0.f;
        if (p >= 0 && p < LQ) {
            const float* s = x + ((size_t)b * CH + ci) * LQ + p;
            vx = fmaxf(s[0], 0.f); vy = fmaxf(s[LQ], 0.f);
        }
        unsigned int u = (__builtin_bit_cast(unsigned int, vx) >> 16)
                       | (__builtin_bit_cast(unsigned int, vy) & 0xFFFF0000u);
        int byte = (j * CH + ci) * 2;
        byte ^= (j & 7) << 4;
        xsu[byte >> 2] = u;
    }
    __syncthreads();

    int l  = tid & 63;
    int w  = tid >> 6;
    int cl = l & 15, hi = l >> 4;
    int co_w = (w & 1) * 32;
    int u_w  = (w >> 1) * 32;

    f32x4 ae[2][2], ao[2][2];
#pragma unroll
    for (int m = 0; m < 2; ++m)
#pragma unroll
        for (int n = 0; n < 2; ++n) {
            ae[m][n] = (f32x4){0.f, 0.f, 0.f, 0.f};
            ao[m][n] = (f32x4){0.f, 0.f, 0.f, 0.f};
        }

    const int TK[4] = {1, 3, 0, 2};
    const int TO[4] = {1, 0, 2, 1};
#pragma unroll
    for (int te = 0; te < 4; ++te) {
        int k = TK[te], off = TO[te];
#pragma unroll
        for (int kb = 0; kb < 4; ++kb) {
            const short* ap = wf + (size_t)((k * 4 + co_w / 16) * 4 + kb) * 512
                            + cl * 32 + hi * 8;
            short8 a[2];
#pragma unroll
            for (int m = 0; m < 2; ++m)
                a[m] = *reinterpret_cast<const short8*>(ap + (size_t)m * 4 * 512);
            short8 bf[2];
#pragma unroll
            for (int n = 0; n < 2; ++n) {
                int tt = u_w + n * 16 + cl + off;
                int byte = (tt * CH + kb * 32 + hi * 8) * 2;
                byte ^= (tt & 7) << 4;
                bf[n] = *reinterpret_cast<const short8*>(
                            reinterpret_cast<const char*>(xsu) + byte);
            }
#pragma unroll
            for (int m = 0; m < 2; ++m)
#pragma unroll
                for (int n = 0; n < 2; ++n) {
                    if (te < 2) ae[m][n] = mfma16(a[m], bf[n], ae[m][n]);
                    else        ao[m][n] = mfma16(a[m], bf[n], ao[m][n]);
                }
        }
    }

#pragma unroll
    for (int m = 0; m < 2; ++m) {
#pragma unroll
        for (int n = 0; n < 2; ++n) {
#pragma unroll
            for (int r = 0; r < 4; ++r) {
                int co = co_w + m * 16 + hi * 4 + r;
                int u  = t0 + u_w + n * 16 + cl;
                float bv = bias[co];
                float2 rr;
                rr.x = fmaxf(ae[m][n][r] + bv, 0.f);
                rr.y = fmaxf(ao[m][n][r] + bv, 0.f);
                *reinterpret_cast<float2*>(&out[((size_t)b * CHH + co) * L1 + 2 * u]) = rr;
            }
        }
    }
}

// ---------------- residual second conv: x += W2 @ relu(h), k=1, 32->128 ----------------
__global__ __launch_bounds__(256) void k_resadd(const float* __restrict__ h,
                                                const float* __restrict__ w2,
                                                float* __restrict__ x) {
    int n = blockIdx.x * 256 + threadIdx.x;
    int t  = n & (LQ - 1);
    int co = (n >> 11) & (CH - 1);
    int b  = n >> 18;
    const float* hp = h + b * CR * LQ + t;
    const float* wp = w2 + co * CR;
    float acc = 0.f;
#pragma unroll
    for (int ci = 0; ci < CR; ++ci)
        acc += wp[ci] * fmaxf(hp[ci * LQ], 0.f);
    x[n] += acc;
}

// ---------------- pvq: z[b,t,d] = bias[d] + sum_ci w[d,ci]*relu(x[b,ci,t]) ----------------
__global__ __launch_bounds__(256) void k_pvqr(const float* __restrict__ x,
                                              const float* __restrict__ w,
                                              const float* __restrict__ bias,
                                              float* __restrict__ z) {
    __shared__ float xs[CH][64];
    __shared__ float wT[CH][64];
    int tid = threadIdx.x;
    int t0 = blockIdx.x * 64;
    int b = blockIdx.y;
    for (int i = tid; i < CD * CH; i += 256) {
        int d = i >> 7, ci = i & 127;
        wT[ci][d] = w[i];
    }
    for (int i = tid; i < CH * 64; i += 256) {
        int ci = i >> 6, j = i & 63;
        xs[ci][j] = fmaxf(x[((size_t)b * CH + ci) * LQ + t0 + j], 0.f);
    }
    __syncthreads();
    int d = tid & 63;
    int tg = tid >> 6;
    float bv = bias[d];
    float acc[16];
#pragma unroll
    for (int i = 0; i < 16; ++i) acc[i] = bv;
    for (int ci = 0; ci < CH; ++ci) {
        float wv = wT[ci][d];
        const float4* xr = reinterpret_cast<const float4*>(&xs[ci][tg * 16]);
        float4 a = xr[0], bq = xr[1], c = xr[2], e = xr[3];
        acc[0]  = fmaf(wv, a.x, acc[0]);
        acc[1]  = fmaf(wv, a.y, acc[1]);
        acc[2]  = fmaf(wv, a.z, acc[2]);
        acc[3]  = fmaf(wv, a.w, acc[3]);
        acc[4]  = fmaf(wv, bq.x, acc[4]);
        acc[5]  = fmaf(wv, bq.y, acc[5]);
        acc[6]  = fmaf(wv, bq.z, acc[6]);
        acc[7]  = fmaf(wv, bq.w, acc[7]);
        acc[8]  = fmaf(wv, c.x, acc[8]);
        acc[9]  = fmaf(wv, c.y, acc[9]);
        acc[10] = fmaf(wv, c.z, acc[10]);
        acc[11] = fmaf(wv, c.w, acc[11]);
        acc[12] = fmaf(wv, e.x, acc[12]);
        acc[13] = fmaf(wv, e.y, acc[13]);
        acc[14] = fmaf(wv, e.z, acc[14]);
        acc[15] = fmaf(wv, e.w, acc[15]);
    }
    int tbase = t0 + tg * 16;
#pragma unroll
    for (int i = 0; i < 16; ++i)
        z[((size_t)b * LQ + tbase + i) * CD + d] = acc[i];
}

// ---------------- cb2[k] = |codebook_k|^2 ----------------
__global__ __launch_bounds__(256) void k_cb2(const float* __restrict__ cb,
                                             float* __restrict__ cb2) {
    int k = blockIdx.x * 256 + threadIdx.x;
    if (k >= NK) return;
    const float* r = cb + k * CD;
    float s = 0.f;
#pragma unroll 8
    for (int i = 0; i < CD; ++i) s += r[i] * r[i];
    cb2[k] = s;
}

// ---------------- VQ via split-precision MFMA: scores = |c|^2 - 2 z.c ----------------
// z = zh + zl (bf16 RNE), -2c = ah + al (bf16 RNE). score = ah.zh + ah.zl + al.zh + |c|^2
// block: 256 thr (4 waves), 256 rows; wave: 64 rows (4 nt tiles of 16)
__global__ __launch_bounds__(256) void k_vqm(const float* __restrict__ z,
                                             const short* __restrict__ cbf_hi,
                                             const short* __restrict__ cbf_lo,
                                             const float* __restrict__ cb2,
                                             const float* __restrict__ cb,
                                             float* __restrict__ q,
                                             int* __restrict__ counts,
                                             float* __restrict__ sse) {
    __shared__ float c2l[NK];         // 2 KB
    __shared__ int   hist[NK];        // 2 KB
    int tid = threadIdx.x;
    int l   = tid & 63;
    int w   = tid >> 6;
    int cl  = l & 15, hi = l >> 4;
    int wrow0 = blockIdx.x * 256 + w * 64;

    for (int i = tid; i < NK; i += 256) { c2l[i] = cb2[i]; hist[i] = 0; }
    __syncthreads();

    // load z fragments, split hi/lo (RNE)
    short8 bh[4][2], bl[4][2];
#pragma unroll
    for (int nt = 0; nt < 4; ++nt) {
        int row = wrow0 + nt * 16 + cl;
        const float* zr = z + (size_t)row * CD;
#pragma unroll
        for (int half = 0; half < 2; ++half) {
            const float4* p4 = reinterpret_cast<const float4*>(zr + half * 32 + hi * 8);
            float4 v0 = p4[0], v1 = p4[1];
            float vs[8] = {v0.x, v0.y, v0.z, v0.w, v1.x, v1.y, v1.z, v1.w};
            short8 sh, sl;
#pragma unroll
            for (int j = 0; j < 8; ++j) {
                unsigned short h = bf16rne(vs[j]);
                float r = vs[j] - bf2f(h);
                sh[j] = (short)h;
                sl[j] = (short)bf16rne(r);
            }
            bh[nt][half] = sh;
            bl[nt][half] = sl;
        }
    }

    float bscore[4];
    int   bidx[4];
#pragma unroll
    for (int nt = 0; nt < 4; ++nt) { bscore[nt] = 1e30f; bidx[nt] = 0; }

#pragma unroll 4
    for (int mt = 0; mt < 32; ++mt) {
        short8 ah0 = *reinterpret_cast<const short8*>(cbf_hi + (mt * 2 + 0) * 512 + l * 8);
        short8 ah1 = *reinterpret_cast<const short8*>(cbf_hi + (mt * 2 + 1) * 512 + l * 8);
        short8 al0 = *reinterpret_cast<const short8*>(cbf_lo + (mt * 2 + 0) * 512 + l * 8);
        short8 al1 = *reinterpret_cast<const short8*>(cbf_lo + (mt * 2 + 1) * 512 + l * 8);
        float4 c2v = *reinterpret_cast<const float4*>(&c2l[mt * 16 + hi * 4]);
        f32x4 cin = (f32x4){c2v.x, c2v.y, c2v.z, c2v.w};
        int mbase = mt * 16 + hi * 4;
#pragma unroll
        for (int nt = 0; nt < 4; ++nt) {
            f32x4 acc = mfma16(al0, bh[nt][0], cin);    // A_lo . z_hi
            acc = mfma16(al1, bh[nt][1], acc);
            acc = mfma16(ah0, bl[nt][0], acc);          // A_hi . z_lo
            acc = mfma16(ah1, bl[nt][1], acc);
            acc = mfma16(ah0, bh[nt][0], acc);          // A_hi . z_hi
            acc = mfma16(ah1, bh[nt][1], acc);
#pragma unroll
            for (int r = 0; r < 4; ++r) {
                float s = acc[r];
                bool better = s < bscore[nt];
                bscore[nt] = better ? s : bscore[nt];
                bidx[nt]   = better ? (mbase + r) : bidx[nt];
            }
        }
    }

    // cross-lane argmin (over hi: lanes xor 16, 32) + fused epilogue
    float err = 0.f;
#pragma unroll
    for (int nt = 0; nt < 4; ++nt) {
        float s = bscore[nt];
        int   id = bidx[nt];
#pragma unroll
        for (int off = 16; off <= 32; off <<= 1) {
            float s2 = __shfl_xor(s, off);
            int   i2 = __shfl_xor(id, off);
            bool take = (s2 < s) || (s2 == s && i2 < id);
            s  = take ? s2 : s;
            id = take ? i2 : id;
        }
        int row = wrow0 + nt * 16 + cl;
        const float4* cbr = reinterpret_cast<const float4*>(cb + (size_t)id * CD);
        float4* qw = reinterpret_cast<float4*>(q + (size_t)row * CD);
        float4 q0 = cbr[hi * 2];
        float4 q1 = cbr[hi * 2 + 1];
        float4 q2 = cbr[8 + hi * 2];
        float4 q3 = cbr[8 + hi * 2 + 1];
        qw[hi * 2]     = q0;
        qw[hi * 2 + 1] = q1;
        qw[8 + hi * 2]     = q2;
        qw[8 + hi * 2 + 1] = q3;
        float qv[16] = {q0.x, q0.y, q0.z, q0.w, q1.x, q1.y, q1.z, q1.w,
                        q2.x, q2.y, q2.z, q2.w, q3.x, q3.y, q3.z, q3.w};
#pragma unroll
        for (int half = 0; half < 2; ++half) {
#pragma unroll
            for (int j = 0; j < 8; ++j) {
                float zv = bf2f((unsigned short)bh[nt][half][j])
                         + bf2f((unsigned short)bl[nt][half][j]);
                float d = qv[half * 8 + j] - zv;
                err = fmaf(d, d, err);
            }
        }
        if (hi == 0) atomicAdd(&hist[id], 1);
    }
#pragma unroll
    for (int s = 32; s > 0; s >>= 1) err += __shfl_xor(err, s);
    if (l == 0) atomicAdd(sse, err);

    __syncthreads();
    for (int i = tid; i < NK; i += 256) {
        int h = hist[i];
        if (h) atomicAdd(&counts[i], h);
    }
}

// ---------------- dt2: ConvT 64->1 k4 s2 p1 -> recon ----------------
__global__ __launch_bounds__(256) void k_dt2(const float* __restrict__ x,
                                             const float* __restrict__ w,
                                             const float* __restrict__ bias,
                                             float* __restrict__ out) {
    int u = blockIdx.x * 256 + threadIdx.x;
    int b = blockIdx.y;
    const float* xp = x + (size_t)b * CHH * L1 + u;
    float bv = bias[0];
    float ae = bv, ao = bv;
    for (int ci = 0; ci < CHH; ++ci) {
        const float* xr = xp + ci * L1;
        float xm  = (u >= 1) ? xr[-1] : 0.f;
        float x0  = xr[0];
        float xp1 = (u < L1 - 1) ? xr[1] : 0.f;
        const float* wc = w + ci * 4;
        ae += wc[1] * x0 + wc[3] * xm;
        ao += wc[0] * xp1 + wc[2] * x0;
    }
    reinterpret_cast<float2*>(out + (size_t)b * L0)[u] = make_float2(ae, ao);
}

// ---------------- finalize: vq_loss + perplexity ----------------
__global__ __launch_bounds__(512) void k_final(const int* __restrict__ counts,
                                               const float* __restrict__ sse,
                                               float* __restrict__ out) {
    __shared__ float red[8];
    int tid = threadIdx.x;
    float p = (float)counts[tid] * (1.f / (float)NROWS);
    float v = p * logf(p + 1e-10f);
#pragma unroll
    for (int s = 32; s > 0; s >>= 1) v += __shfl_down(v, s);
    if ((tid & 63) == 0) red[tid >> 6] = v;
    __syncthreads();
    if (tid == 0) {
        float tot = 0.f;
        for (int i = 0; i < 8; ++i) tot += red[i];
        out[524288] = 1.25f * sse[0] / ((float)NROWS * (float)CD);
        out[524289] = expf(-tot);
    }
}

extern "C" void kernel_launch(void* const* d_in, const int* in_sizes, int n_in,
                              void* d_out, int out_size, void* d_ws, size_t ws_size,
                              hipStream_t stream) {
    const float* x      = (const float*)d_in[0];
    const float* ec1_w  = (const float*)d_in[1];
    const float* ec1_b  = (const float*)d_in[2];
    const float* ec2_w  = (const float*)d_in[3];
    const float* ec2_b  = (const float*)d_in[4];
    const float* ec3_w  = (const float*)d_in[5];
    const float* ec3_b  = (const float*)d_in[6];
    const float* er1_w1 = (const float*)d_in[7];
    const float* er1_w2 = (const float*)d_in[8];
    const float* er2_w1 = (const float*)d_in[9];
    const float* er2_w2 = (const float*)d_in[10];
    const float* pvq_w  = (const float*)d_in[11];
    const float* pvq_b  = (const float*)d_in[12];
    const float* cbk    = (const float*)d_in[13];
    const float* dc1_w  = (const float*)d_in[14];
    const float* dc1_b  = (const float*)d_in[15];
    const float* dr1_w1 = (const float*)d_in[16];
    const float* dr1_w2 = (const float*)d_in[17];
    const float* dr2_w1 = (const float*)d_in[18];
    const float* dr2_w2 = (const float*)d_in[19];
    const float* dt1_w  = (const float*)d_in[20];
    const float* dt1_b  = (const float*)d_in[21];
    const float* dt2_w  = (const float*)d_in[22];
    const float* dt2_b  = (const float*)d_in[23];
    float* out = (float*)d_out;

    char* ws = (char*)d_ws;
    float* A    = (float*)(ws);                        // 64 MB
    float* Bb   = (float*)(ws + 67108864);             // 64 MB
    char*  smal = ws + 134217728;
    int*   counts = (int*)smal;                        // 2048 B
    float* sse    = (float*)(smal + 2048);             // 4 B
    float* cb2    = (float*)(smal + 4096);             // 2048 B
    short* wf_ec2 = (short*)(smal + 8192);             // 32768 sh
    short* wf_ec3 = wf_ec2 + 32768;                    // 49152 sh
    short* wf_er1 = wf_ec3 + 49152;                    // 12288 sh
    short* wf_er2 = wf_er1 + 12288;
    short* wf_dc1 = wf_er2 + 12288;                    // 24576 sh
    short* wf_dr1 = wf_dc1 + 24576;
    short* wf_dr2 = wf_dr1 + 12288;
    short* wf_dt1 = wf_dr2 + 12288;                    // 32768 sh
    short* cbf_hi = wf_dt1 + 32768;                    // 32768 sh
    short* cbf_lo = cbf_hi + 32768;                    // 32768 sh
    float* z = Bb;                                     // 32 MB  [B,2048,64]
    float* q = Bb + 8388608;                           // 32 MB  [B,2048,64]

    hipMemsetAsync(smal, 0, 2056, stream);

    // weight / codebook fragment prep (tiny)
    k_wtf<<<dim3(128), 256, 0, stream>>>(ec2_w, wf_ec2, 128, 64, 4, 0);
    k_wtf<<<dim3(192), 256, 0, stream>>>(ec3_w, wf_ec3, 128, 128, 3, 0);
    k_wtf<<<dim3(48), 256, 0, stream>>>(er1_w1, wf_er1, 32, 128, 3, 0);
    k_wtf<<<dim3(48), 256, 0, stream>>>(er2_w1, wf_er2, 32, 128, 3, 0);
    k_wtf<<<dim3(96), 256, 0, stream>>>(dc1_w, wf_dc1, 128, 64, 3, 0);
    k_wtf<<<dim3(48), 256, 0, stream>>>(dr1_w1, wf_dr1, 32, 128, 3, 0);
    k_wtf<<<dim3(48), 256, 0, stream>>>(dr2_w1, wf_dr2, 32, 128, 3, 0);
    k_wtf<<<dim3(128), 256, 0, stream>>>(dt1_w, wf_dt1, 64, 128, 4, 1);
    k_cbf<<<dim3(128), 256, 0, stream>>>(cbk, cbf_hi, cbf_lo);
    k_cb2<<<dim3(2), 256, 0, stream>>>(cbk, cb2);

    // encoder
    k_ec1<<<dim3((NB * CHH * L1) / 256), 256, 0, stream>>>(x, ec1_w, ec1_b, A);
    k_mfconv2<64, 128, 4, 2, 1, L1, false, false, true, true>
        <<<dim3(LQ / 64, 1, NB), 256, 0, stream>>>(A, wf_ec2, ec2_b, Bb);
    k_mfconv2<128, 128, 3, 1, 0, LQ, false, false, true, false>
        <<<dim3(LQ / 64, 1, NB), 256, 0, stream>>>(Bb, wf_ec3, ec3_b, A);
    float* HmidE = Bb;
    k_mfconv2<128, 32, 3, 1, 0, LQ, true, false, false, false>
        <<<dim3(LQ / 64, 1, NB), 256, 0, stream>>>(A, wf_er1, nullptr, HmidE);
    k_resadd<<<dim3((NB * CH * LQ) / 256), 256, 0, stream>>>(HmidE, er1_w2, A);
    k_mfconv2<128, 32, 3, 1, 0, LQ, true, false, false, false>
        <<<dim3(LQ / 64, 1, NB), 256, 0, stream>>>(A, wf_er2, nullptr, HmidE);
    k_resadd<<<dim3((NB * CH * LQ) / 256), 256, 0, stream>>>(HmidE, er2_w2, A);
    k_pvqr<<<dim3(LQ / 64, NB), 256, 0, stream>>>(A, pvq_w, pvq_b, z);

    // vector quantizer (split-precision MFMA argmin + fused gather/SSE/hist)
    k_vqm<<<dim3(NROWS / 256), 256, 0, stream>>>(z, cbf_hi, cbf_lo, cb2, cbk,
                                                 q, counts, sse);

    // decoder
    k_mfconv2<64, 128, 3, 1, 0, LQ, false, true, true, false>
        <<<dim3(LQ / 64, 1, NB), 256, 0, stream>>>(q, wf_dc1, dc1_b, A);
    float* HmidD = Bb;
    k_mfconv2<128, 32, 3, 1, 0, LQ, true, false, false, false>
        <<<dim3(LQ / 64, 1, NB), 256, 0, stream>>>(A, wf_dr1, nullptr, HmidD);
    k_resadd<<<dim3((NB * CH * LQ) / 256), 256, 0, stream>>>(HmidD, dr1_w2, A);
    k_mfconv2<128, 32, 3, 1, 0, LQ, true, false, false, false>
        <<<dim3(LQ / 64, 1, NB), 256, 0, stream>>>(A, wf_dr2, nullptr, HmidD);
    k_resadd<<<dim3((NB * CH * LQ) / 256), 256, 0, stream>>>(HmidD, dr2_w2, A);
    k_dt1m<<<dim3(LQ / 64, 1, NB), 256, 0, stream>>>(A, wf_dt1, dt1_b, Bb);
    k_dt2<<<dim3(L1 / 256, NB), 256, 0, stream>>>(Bb, dt2_w, dt2_b, out);

    // scalars
    k_final<<<dim3(1), 512, 0, stream>>>(counts, sse, out);
}

// Round 7
// 678.282 us; speedup vs baseline: 7.7579x; 1.6284x over previous
//
#include <hip/hip_runtime.h>
#include <math.h>

// Problem constants
static constexpr int NB  = 64;     // batch
static constexpr int L0  = 8192;   // input length
static constexpr int L1  = 4096;   // after ec1
static constexpr int LQ  = 2048;   // latent length
static constexpr int CH  = 128;    // hidden H
static constexpr int CHH = 64;     // H/2
static constexpr int CR  = 32;     // residual hidden
static constexpr int CD  = 64;     // codebook dim D
static constexpr int NK  = 512;    // codebook size K
static constexpr int NROWS = NB * LQ;  // 131072 latent vectors

using short8 = __attribute__((ext_vector_type(8))) short;
using f32x4  = __attribute__((ext_vector_type(4))) float;

__device__ inline f32x4 mfma16(short8 a, short8 b, f32x4 c) {
    return __builtin_amdgcn_mfma_f32_16x16x32_bf16(a, b, c, 0, 0, 0);
}

__device__ inline unsigned short bf16rne(float v) {
    unsigned int bb = __builtin_bit_cast(unsigned int, v);
    unsigned int r = (bb + 0x7FFFu + ((bb >> 16) & 1u)) >> 16;
    return (unsigned short)r;
}
__device__ inline float bf2f(unsigned short s) {
    unsigned int u = ((unsigned int)s) << 16;
    return __builtin_bit_cast(float, u);
}

// ---- conv weight->fragment prep: dst [tap][cb][kb][cl*32+hi*8+j] bf16 ----
__global__ __launch_bounds__(256) void k_wtf(const float* __restrict__ src,
                                             short* __restrict__ dst,
                                             int CO, int CI, int K, int iok) {
    int i = blockIdx.x * 256 + threadIdx.x;
    int total = K * CO * CI;
    if (i >= total) return;
    int j  = i & 7;
    int hi = (i >> 3) & 3;
    int cl = (i >> 5) & 15;
    int rest = i >> 9;
    int CIb = CI >> 5, COb = CO >> 4;
    int kb = rest % CIb; rest /= CIb;
    int cb = rest % COb;
    int tap = rest / COb;
    int co = cb * 16 + cl, ci = kb * 32 + hi * 8 + j;
    float v = iok ? src[(ci * CO + co) * K + tap] : src[(co * CI + ci) * K + tap];
    dst[i] = (short)bf16rne(v);
}

// ---- k=1 weight frag prep with hi/lo split: CO=128, CI=32 ----
__global__ __launch_bounds__(256) void k_w2f(const float* __restrict__ src,
                                             short* __restrict__ hi_dst,
                                             short* __restrict__ lo_dst) {
    int i = blockIdx.x * 256 + threadIdx.x;   // 4096
    if (i >= CH * CR) return;
    int j  = i & 7;
    int hi = (i >> 3) & 3;
    int cl = (i >> 5) & 15;
    int cb = i >> 9;
    int co = cb * 16 + cl, ci = hi * 8 + j;
    float v = src[co * CR + ci];
    unsigned short h = bf16rne(v);
    hi_dst[i] = (short)h;
    lo_dst[i] = (short)bf16rne(v - bf2f(h));
}

// ---- codebook A-frag prep, split precision: -2*cb = hi + lo (both bf16) ----
__global__ __launch_bounds__(256) void k_cbf(const float* __restrict__ cb,
                                             short* __restrict__ hi_dst,
                                             short* __restrict__ lo_dst) {
    int i = blockIdx.x * 256 + threadIdx.x;   // 32768
    if (i >= NK * CD) return;
    int j    = i & 7;
    int l    = (i >> 3) & 63;
    int half = (i >> 9) & 1;
    int mt   = i >> 10;
    int cl = l & 15, hi = l >> 4;
    int m = mt * 16 + cl;
    int k = half * 32 + hi * 8 + j;
    float v = -2.f * cb[m * CD + k];
    unsigned short h = bf16rne(v);
    float r = v - bf2f(h);
    hi_dst[i] = (short)h;
    lo_dst[i] = (short)bf16rne(r);
}

// ---------------- ec1: [B,1,8192] -> [B,64,4096], k4 s2 p1, bias+ReLU ----------------
__global__ __launch_bounds__(256) void k_ec1(const float* __restrict__ x,
                                             const float* __restrict__ w,
                                             const float* __restrict__ bias,
                                             float* __restrict__ out) {
    int n = blockIdx.x * 256 + threadIdx.x;
    int t  = n & (L1 - 1);
    int co = (n >> 12) & (CHH - 1);
    int b  = n >> 18;
    const float* xp = x + b * L0;
    float acc = bias[co];
    int p0 = 2 * t - 1;
#pragma unroll
    for (int k = 0; k < 4; ++k) {
        int p = p0 + k;
        if (p >= 0 && p < L0) acc += w[co * 4 + k] * xp[p];
    }
    out[n] = fmaxf(acc, 0.f);
}

// ---------------- MFMA conv v2: bf16 swizzled LDS [t][ci], ds_read_b128 B-frags -------
template <int CIN, int COUT, int NTAPS, int TSTRIDE, int SWS, int LIN,
          bool RELU_IN, bool TRANS_IN, bool HAS_BIAS, bool RELU_OUT>
__global__ __launch_bounds__(256) void k_mfconv2(const float* __restrict__ x,
                                                 const short* __restrict__ wf,
                                                 const float* __restrict__ bias,
                                                 float* __restrict__ out) {
    constexpr int XW = 63 * TSTRIDE + NTAPS;
    constexpr int MR = (COUT == 128) ? 4 : 1;
    constexpr int COb = COUT / 16, CIb = CIN / 32;
    __shared__ unsigned int xsu[CIN * XW / 2];
    int t0 = blockIdx.x * 64;
    int b  = blockIdx.z;
    int tid = threadIdx.x;

    if (TRANS_IN) {
        for (int i = tid; i < XW * (CIN / 2); i += 256) {
            int j = i / (CIN / 2);
            int ci = (i - j * (CIN / 2)) * 2;
            int p = t0 - 1 + j;
            float vx = 0.f, vy = 0.f;
            if (p >= 0 && p < LIN) {
                const float* s = x + ((size_t)b * LIN + p) * CIN + ci;
                vx = s[0]; vy = s[1];
            }
            if (RELU_IN) { vx = fmaxf(vx, 0.f); vy = fmaxf(vy, 0.f); }
            unsigned int u = (__builtin_bit_cast(unsigned int, vx) >> 16)
                           | (__builtin_bit_cast(unsigned int, vy) & 0xFFFF0000u);
            int byte = (j * CIN + ci) * 2;
            byte ^= ((j >> SWS) & 7) << 4;
            xsu[byte >> 2] = u;
        }
    } else {
        for (int i = tid; i < (CIN / 2) * XW; i += 256) {
            int ci2 = i / XW;
            int j = i - ci2 * XW;
            int ci = ci2 * 2;
            int p = t0 * TSTRIDE - 1 + j;
            float vx = 0.f, vy = 0.f;
            if (p >= 0 && p < LIN) {
                const float* s = x + ((size_t)b * CIN + ci) * LIN + p;
                vx = s[0]; vy = s[LIN];
            }
            if (RELU_IN) { vx = fmaxf(vx, 0.f); vy = fmaxf(vy, 0.f); }
            unsigned int u = (__builtin_bit_cast(unsigned int, vx) >> 16)
                           | (__builtin_bit_cast(unsigned int, vy) & 0xFFFF0000u);
            int byte = (j * CIN + ci) * 2;
            byte ^= ((j >> SWS) & 7) << 4;
            xsu[byte >> 2] = u;
        }
    }
    __syncthreads();

    int l  = tid & 63;
    int w  = tid >> 6;
    int cl = l & 15, hi = l >> 4;
    int co_w = (w & 1) * (MR * 16);
    int t_w  = (w >> 1) * 32;

    f32x4 acc[MR][2];
#pragma unroll
    for (int m = 0; m < MR; ++m)
#pragma unroll
        for (int n = 0; n < 2; ++n) acc[m][n] = (f32x4){0.f, 0.f, 0.f, 0.f};

#pragma unroll
    for (int tap = 0; tap < NTAPS; ++tap) {
#pragma unroll
        for (int kb = 0; kb < CIb; ++kb) {
            const short* ap = wf + ((size_t)((tap * COb + co_w / 16) * CIb + kb)) * 512
                            + cl * 32 + hi * 8;
            short8 a[MR];
#pragma unroll
            for (int m = 0; m < MR; ++m)
                a[m] = *reinterpret_cast<const short8*>(ap + (size_t)m * CIb * 512);
            short8 bf[2];
#pragma unroll
            for (int n = 0; n < 2; ++n) {
                int tt = (t_w + n * 16 + cl) * TSTRIDE + tap;
                int byte = (tt * CIN + kb * 32 + hi * 8) * 2;
                byte ^= ((tt >> SWS) & 7) << 4;
                bf[n] = *reinterpret_cast<const short8*>(
                            reinterpret_cast<const char*>(xsu) + byte);
            }
#pragma unroll
            for (int m = 0; m < MR; ++m)
#pragma unroll
                for (int n = 0; n < 2; ++n)
                    acc[m][n] = mfma16(a[m], bf[n], acc[m][n]);
        }
    }

#pragma unroll
    for (int m = 0; m < MR; ++m) {
#pragma unroll
        for (int n = 0; n < 2; ++n) {
#pragma unroll
            for (int r = 0; r < 4; ++r) {
                int co = co_w + m * 16 + hi * 4 + r;
                int t  = t0 + t_w + n * 16 + cl;
                float v = acc[m][n][r];
                if (HAS_BIAS) v += bias[co];
                if (RELU_OUT) v = fmaxf(v, 0.f);
                out[((size_t)b * COUT + co) * LQ + t] = v;
            }
        }
    }
}

// ---------------- fused residual block: dst = src + W2 . relu(conv3(relu(src))) --------
// stage1: h(32x64) via MFMA from swizzled bf16 x-tile; relu+split h -> LDS hi/lo;
// stage2: split-precision k=1 MFMA; epilogue adds fp32 src.
__global__ __launch_bounds__(256) void k_resblk(const float* __restrict__ src,
                                                float* __restrict__ dst,
                                                const short* __restrict__ wf1,
                                                const short* __restrict__ w2h,
                                                const short* __restrict__ w2l) {
    constexpr int XW = 66;
    __shared__ unsigned int xsu[CH * XW / 2];   // 16896 B
    __shared__ unsigned int hh[64 * 16];        // [t][ciu] hi, 4 KB
    __shared__ unsigned int hl[64 * 16];        // lo, 4 KB
    int t0 = blockIdx.x * 64;
    int b  = blockIdx.z;
    int tid = threadIdx.x;

    for (int i = tid; i < (CH / 2) * XW; i += 256) {
        int ci2 = i / XW;
        int j = i - ci2 * XW;
        int ci = ci2 * 2;
        int p = t0 - 1 + j;
        float vx = 0.f, vy = 0.f;
        if (p >= 0 && p < LQ) {
            const float* s = src + ((size_t)b * CH + ci) * LQ + p;
            vx = fmaxf(s[0], 0.f); vy = fmaxf(s[LQ], 0.f);
        }
        unsigned int u = (__builtin_bit_cast(unsigned int, vx) >> 16)
                       | (__builtin_bit_cast(unsigned int, vy) & 0xFFFF0000u);
        int byte = (j * CH + ci) * 2;
        byte ^= (j & 7) << 4;
        xsu[byte >> 2] = u;
    }
    __syncthreads();

    int l  = tid & 63;
    int w  = tid >> 6;
    int cl = l & 15, hi = l >> 4;
    int co_w1 = (w & 1) * 16;     // h-channel tile base (0 or 16)
    int t_w   = (w >> 1) * 32;    // t base (0..32)

    // ---- stage 1: h = conv3(relu(x)) ----
    f32x4 acc1[2];
    acc1[0] = (f32x4){0.f, 0.f, 0.f, 0.f};
    acc1[1] = (f32x4){0.f, 0.f, 0.f, 0.f};
#pragma unroll
    for (int tap = 0; tap < 3; ++tap) {
#pragma unroll
        for (int kb = 0; kb < 4; ++kb) {
            const short* ap = wf1 + ((size_t)((tap * 2 + (w & 1)) * 4 + kb)) * 512
                            + cl * 32 + hi * 8;
            short8 a = *reinterpret_cast<const short8*>(ap);
#pragma unroll
            for (int n = 0; n < 2; ++n) {
                int tt = (t_w + n * 16 + cl) + tap;
                int byte = (tt * CH + kb * 32 + hi * 8) * 2;
                byte ^= (tt & 7) << 4;
                short8 bf = *reinterpret_cast<const short8*>(
                                reinterpret_cast<const char*>(xsu) + byte);
                acc1[n] = mfma16(a, bf, acc1[n]);
            }
        }
    }

    // relu + hi/lo split -> h LDS [t][ciu] (u32 = 2 bf16), swizzle idx ^= (t&3)<<2
#pragma unroll
    for (int n = 0; n < 2; ++n) {
        int t = t_w + n * 16 + cl;
#pragma unroll
        for (int rp = 0; rp < 2; ++rp) {
            float v0 = fmaxf(acc1[n][2 * rp], 0.f);
            float v1 = fmaxf(acc1[n][2 * rp + 1], 0.f);
            unsigned short h0 = bf16rne(v0), h1 = bf16rne(v1);
            unsigned short l0 = bf16rne(v0 - bf2f(h0)), l1 = bf16rne(v1 - bf2f(h1));
            int ciu = (co_w1 >> 1) + hi * 2 + rp;
            int idx = t * 16 + (ciu ^ ((t & 3) << 2));
            hh[idx] = (unsigned int)h0 | ((unsigned int)h1 << 16);
            hl[idx] = (unsigned int)l0 | ((unsigned int)l1 << 16);
        }
    }
    __syncthreads();

    // ---- stage 2: res = W2 . relu(h), split precision; dst = src + res ----
    int co2_w = (w & 1) * 64;
    short8 bh[2], bl[2];
#pragma unroll
    for (int n2 = 0; n2 < 2; ++n2) {
        int t = t_w + n2 * 16 + cl;
        int idx = t * 16 + ((hi * 4) ^ ((t & 3) << 2));
        bh[n2] = *reinterpret_cast<const short8*>(&hh[idx]);
        bl[n2] = *reinterpret_cast<const short8*>(&hl[idx]);
    }
#pragma unroll
    for (int m2 = 0; m2 < 4; ++m2) {
        int co2 = co2_w + m2 * 16;
        const short* aph = w2h + (co2 / 16) * 512 + cl * 32 + hi * 8;
        const short* apl = w2l + (co2 / 16) * 512 + cl * 32 + hi * 8;
        short8 ah = *reinterpret_cast<const short8*>(aph);
        short8 al = *reinterpret_cast<const short8*>(apl);
#pragma unroll
        for (int n2 = 0; n2 < 2; ++n2) {
            f32x4 acc = (f32x4){0.f, 0.f, 0.f, 0.f};
            acc = mfma16(ah, bl[n2], acc);
            acc = mfma16(al, bh[n2], acc);
            acc = mfma16(ah, bh[n2], acc);
            int t = t0 + t_w + n2 * 16 + cl;
#pragma unroll
            for (int r = 0; r < 4; ++r) {
                int co = co2 + hi * 4 + r;
                size_t off = ((size_t)b * CH + co) * LQ + t;
                dst[off] = src[off] + acc[r];
            }
        }
    }
}

// ---------------- dt1 MFMA v2: ConvT 128->64 k4 s2 p1, relu(in), relu(out) -------------
__global__ __launch_bounds__(256) void k_dt1m(const float* __restrict__ x,
                                              const short* __restrict__ wf,  // IOK frags
                                              const float* __restrict__ bias,
                                              float* __restrict__ out) {
    constexpr int XW = 66;
    __shared__ unsigned int xsu[CH * XW / 2];
    int t0 = blockIdx.x * 64;     // u-range base
    int b  = blockIdx.z;
    int tid = threadIdx.x;
    for (int i = tid; i < (CH / 2) * XW; i += 256) {
        int ci2 = i / XW;
        int j = i - ci2 * XW;
        int ci = ci2 * 2;
        int p = t0 - 1 + j;
        float vx = 0.f, vy = 0.f;
        if (p >= 0 && p < LQ) {
            const float* s = x + ((size_t)b * CH + ci) * LQ + p;
            vx = fmaxf(s[0], 0.f); vy = fmaxf(s[LQ], 0.f);
        }
        unsigned int u = (__builtin_bit_cast(unsigned int, vx) >> 16)
                       | (__builtin_bit_cast(unsigned int, vy) & 0xFFFF0000u);
        int byte = (j * CH + ci) * 2;
        byte ^= (j & 7) << 4;
        xsu[byte >> 2] = u;
    }
    __syncthreads();

    int l  = tid & 63;
    int w  = tid >> 6;
    int cl = l & 15, hi = l >> 4;
    int co_w = (w & 1) * 32;
    int u_w  = (w >> 1) * 32;

    f32x4 ae[2][2], ao[2][2];
#pragma unroll
    for (int m = 0; m < 2; ++m)
#pragma unroll
        for (int n = 0; n < 2; ++n) {
            ae[m][n] = (f32x4){0.f, 0.f, 0.f, 0.f};
            ao[m][n] = (f32x4){0.f, 0.f, 0.f, 0.f};
        }

    const int TK[4] = {1, 3, 0, 2};
    const int TO[4] = {1, 0, 2, 1};
#pragma unroll
    for (int te = 0; te < 4; ++te) {
        int k = TK[te], off = TO[te];
#pragma unroll
        for (int kb = 0; kb < 4; ++kb) {
            const short* ap = wf + (size_t)((k * 4 + co_w / 16) * 4 + kb) * 512
                            + cl * 32 + hi * 8;
            short8 a[2];
#pragma unroll
            for (int m = 0; m < 2; ++m)
                a[m] = *reinterpret_cast<const short8*>(ap + (size_t)m * 4 * 512);
            short8 bf[2];
#pragma unroll
            for (int n = 0; n < 2; ++n) {
                int tt = u_w + n * 16 + cl + off;
                int byte = (tt * CH + kb * 32 + hi * 8) * 2;
                byte ^= (tt & 7) << 4;
                bf[n] = *reinterpret_cast<const short8*>(
                            reinterpret_cast<const char*>(xsu) + byte);
            }
#pragma unroll
            for (int m = 0; m < 2; ++m)
#pragma unroll
                for (int n = 0; n < 2; ++n) {
                    if (te < 2) ae[m][n] = mfma16(a[m], bf[n], ae[m][n]);
                    else        ao[m][n] = mfma16(a[m], bf[n], ao[m][n]);
                }
        }
    }

#pragma unroll
    for (int m = 0; m < 2; ++m) {
#pragma unroll
        for (int n = 0; n < 2; ++n) {
#pragma unroll
            for (int r = 0; r < 4; ++r) {
                int co = co_w + m * 16 + hi * 4 + r;
                int u  = t0 + u_w + n * 16 + cl;
                float bv = bias[co];
                float2 rr;
                rr.x = fmaxf(ae[m][n][r] + bv, 0.f);
                rr.y = fmaxf(ao[m][n][r] + bv, 0.f);
                *reinterpret_cast<float2*>(&out[((size_t)b * CHH + co) * L1 + 2 * u]) = rr;
            }
        }
    }
}

// ---------------- pvq: z[b,t,d] = bias[d] + sum_ci w[d,ci]*relu(x[b,ci,t]) ----------------
__global__ __launch_bounds__(256) void k_pvqr(const float* __restrict__ x,
                                              const float* __restrict__ w,
                                              const float* __restrict__ bias,
                                              float* __restrict__ z) {
    __shared__ float xs[CH][64];
    __shared__ float wT[CH][64];
    int tid = threadIdx.x;
    int t0 = blockIdx.x * 64;
    int b = blockIdx.y;
    for (int i = tid; i < CD * CH; i += 256) {
        int d = i >> 7, ci = i & 127;
        wT[ci][d] = w[i];
    }
    for (int i = tid; i < CH * 64; i += 256) {
        int ci = i >> 6, j = i & 63;
        xs[ci][j] = fmaxf(x[((size_t)b * CH + ci) * LQ + t0 + j], 0.f);
    }
    __syncthreads();
    int d = tid & 63;
    int tg = tid >> 6;
    float bv = bias[d];
    float acc[16];
#pragma unroll
    for (int i = 0; i < 16; ++i) acc[i] = bv;
    for (int ci = 0; ci < CH; ++ci) {
        float wv = wT[ci][d];
        const float4* xr = reinterpret_cast<const float4*>(&xs[ci][tg * 16]);
        float4 a = xr[0], bq = xr[1], c = xr[2], e = xr[3];
        acc[0]  = fmaf(wv, a.x, acc[0]);
        acc[1]  = fmaf(wv, a.y, acc[1]);
        acc[2]  = fmaf(wv, a.z, acc[2]);
        acc[3]  = fmaf(wv, a.w, acc[3]);
        acc[4]  = fmaf(wv, bq.x, acc[4]);
        acc[5]  = fmaf(wv, bq.y, acc[5]);
        acc[6]  = fmaf(wv, bq.z, acc[6]);
        acc[7]  = fmaf(wv, bq.w, acc[7]);
        acc[8]  = fmaf(wv, c.x, acc[8]);
        acc[9]  = fmaf(wv, c.y, acc[9]);
        acc[10] = fmaf(wv, c.z, acc[10]);
        acc[11] = fmaf(wv, c.w, acc[11]);
        acc[12] = fmaf(wv, e.x, acc[12]);
        acc[13] = fmaf(wv, e.y, acc[13]);
        acc[14] = fmaf(wv, e.z, acc[14]);
        acc[15] = fmaf(wv, e.w, acc[15]);
    }
    int tbase = t0 + tg * 16;
#pragma unroll
    for (int i = 0; i < 16; ++i)
        z[((size_t)b * LQ + tbase + i) * CD + d] = acc[i];
}

// ---------------- cb2[k] = |codebook_k|^2 ----------------
__global__ __launch_bounds__(256) void k_cb2(const float* __restrict__ cb,
                                             float* __restrict__ cb2) {
    int k = blockIdx.x * 256 + threadIdx.x;
    if (k >= NK) return;
    const float* r = cb + k * CD;
    float s = 0.f;
#pragma unroll 8
    for (int i = 0; i < CD; ++i) s += r[i] * r[i];
    cb2[k] = s;
}

// ---------------- VQ via split-precision MFMA: scores = |c|^2 - 2 z.c ----------------
__global__ __launch_bounds__(256) void k_vqm(const float* __restrict__ z,
                                             const short* __restrict__ cbf_hi,
                                             const short* __restrict__ cbf_lo,
                                             const float* __restrict__ cb2,
                                             const float* __restrict__ cb,
                                             float* __restrict__ q,
                                             int* __restrict__ counts,
                                             float* __restrict__ sse) {
    __shared__ float c2l[NK];         // 2 KB
    __shared__ int   hist[NK];        // 2 KB
    int tid = threadIdx.x;
    int l   = tid & 63;
    int w   = tid >> 6;
    int cl  = l & 15, hi = l >> 4;
    int wrow0 = blockIdx.x * 256 + w * 64;

    for (int i = tid; i < NK; i += 256) { c2l[i] = cb2[i]; hist[i] = 0; }
    __syncthreads();

    // load z fragments, split hi/lo (RNE)
    short8 bh[4][2], bl[4][2];
#pragma unroll
    for (int nt = 0; nt < 4; ++nt) {
        int row = wrow0 + nt * 16 + cl;
        const float* zr = z + (size_t)row * CD;
#pragma unroll
        for (int half = 0; half < 2; ++half) {
            const float4* p4 = reinterpret_cast<const float4*>(zr + half * 32 + hi * 8);
            float4 v0 = p4[0], v1 = p4[1];
            float vs[8] = {v0.x, v0.y, v0.z, v0.w, v1.x, v1.y, v1.z, v1.w};
            short8 sh, sl;
#pragma unroll
            for (int j = 0; j < 8; ++j) {
                unsigned short h = bf16rne(vs[j]);
                float r = vs[j] - bf2f(h);
                sh[j] = (short)h;
                sl[j] = (short)bf16rne(r);
            }
            bh[nt][half] = sh;
            bl[nt][half] = sl;
        }
    }

    float bscore[4];
    int   bidx[4];
#pragma unroll
    for (int nt = 0; nt < 4; ++nt) { bscore[nt] = 1e30f; bidx[nt] = 0; }

#pragma unroll 4
    for (int mt = 0; mt < 32; ++mt) {
        short8 ah0 = *reinterpret_cast<const short8*>(cbf_hi + (mt * 2 + 0) * 512 + l * 8);
        short8 ah1 = *reinterpret_cast<const short8*>(cbf_hi + (mt * 2 + 1) * 512 + l * 8);
        short8 al0 = *reinterpret_cast<const short8*>(cbf_lo + (mt * 2 + 0) * 512 + l * 8);
        short8 al1 = *reinterpret_cast<const short8*>(cbf_lo + (mt * 2 + 1) * 512 + l * 8);
        float4 c2v = *reinterpret_cast<const float4*>(&c2l[mt * 16 + hi * 4]);
        f32x4 cin = (f32x4){c2v.x, c2v.y, c2v.z, c2v.w};
        int mbase = mt * 16 + hi * 4;
#pragma unroll
        for (int nt = 0; nt < 4; ++nt) {
            f32x4 acc = mfma16(al0, bh[nt][0], cin);    // A_lo . z_hi
            acc = mfma16(al1, bh[nt][1], acc);
            acc = mfma16(ah0, bl[nt][0], acc);          // A_hi . z_lo
            acc = mfma16(ah1, bl[nt][1], acc);
            acc = mfma16(ah0, bh[nt][0], acc);          // A_hi . z_hi
            acc = mfma16(ah1, bh[nt][1], acc);
#pragma unroll
            for (int r = 0; r < 4; ++r) {
                float s = acc[r];
                bool better = s < bscore[nt];
                bscore[nt] = better ? s : bscore[nt];
                bidx[nt]   = better ? (mbase + r) : bidx[nt];
            }
        }
    }

    // cross-lane argmin + fused epilogue (q gather exact f32, SSE, hist)
    float err = 0.f;
#pragma unroll
    for (int nt = 0; nt < 4; ++nt) {
        float s = bscore[nt];
        int   id = bidx[nt];
#pragma unroll
        for (int off = 16; off <= 32; off <<= 1) {
            float s2 = __shfl_xor(s, off);
            int   i2 = __shfl_xor(id, off);
            bool take = (s2 < s) || (s2 == s && i2 < id);
            s  = take ? s2 : s;
            id = take ? i2 : id;
        }
        int row = wrow0 + nt * 16 + cl;
        const float4* cbr = reinterpret_cast<const float4*>(cb + (size_t)id * CD);
        float4* qw = reinterpret_cast<float4*>(q + (size_t)row * CD);
        float4 q0 = cbr[hi * 2];
        float4 q1 = cbr[hi * 2 + 1];
        float4 q2 = cbr[8 + hi * 2];
        float4 q3 = cbr[8 + hi * 2 + 1];
        qw[hi * 2]     = q0;
        qw[hi * 2 + 1] = q1;
        qw[8 + hi * 2]     = q2;
        qw[8 + hi * 2 + 1] = q3;
        float qv[16] = {q0.x, q0.y, q0.z, q0.w, q1.x, q1.y, q1.z, q1.w,
                        q2.x, q2.y, q2.z, q2.w, q3.x, q3.y, q3.z, q3.w};
#pragma unroll
        for (int half = 0; half < 2; ++half) {
#pragma unroll
            for (int j = 0; j < 8; ++j) {
                float zv = bf2f((unsigned short)bh[nt][half][j])
                         + bf2f((unsigned short)bl[nt][half][j]);
                float d = qv[half * 8 + j] - zv;
                err = fmaf(d, d, err);
            }
        }
        if (hi == 0) atomicAdd(&hist[id], 1);
    }
#pragma unroll
    for (int s = 32; s > 0; s >>= 1) err += __shfl_xor(err, s);
    if (l == 0) atomicAdd(sse, err);

    __syncthreads();
    for (int i = tid; i < NK; i += 256) {
        int h = hist[i];
        if (h) atomicAdd(&counts[i], h);
    }
}

// ---------------- dt2: ConvT 64->1 k4 s2 p1 -> recon ----------------
__global__ __launch_bounds__(256) void k_dt2(const float* __restrict__ x,
                                             const float* __restrict__ w,
                                             const float* __restrict__ bias,
                                             float* __restrict__ out) {
    int u = blockIdx.x * 256 + threadIdx.x;
    int b = blockIdx.y;
    const float* xp = x + (size_t)b * CHH * L1 + u;
    float bv = bias[0];
    float ae = bv, ao = bv;
    for (int ci = 0; ci < CHH; ++ci) {
        const float* xr = xp + ci * L1;
        float xm  = (u >= 1) ? xr[-1] : 0.f;
        float x0  = xr[0];
        float xp1 = (u < L1 - 1) ? xr[1] : 0.f;
        const float* wc = w + ci * 4;
        ae += wc[1] * x0 + wc[3] * xm;
        ao += wc[0] * xp1 + wc[2] * x0;
    }
    reinterpret_cast<float2*>(out + (size_t)b * L0)[u] = make_float2(ae, ao);
}

// ---------------- finalize: vq_loss + perplexity ----------------
__global__ __launch_bounds__(512) void k_final(const int* __restrict__ counts,
                                               const float* __restrict__ sse,
                                               float* __restrict__ out) {
    __shared__ float red[8];
    int tid = threadIdx.x;
    float p = (float)counts[tid] * (1.f / (float)NROWS);
    float v = p * logf(p + 1e-10f);
#pragma unroll
    for (int s = 32; s > 0; s >>= 1) v += __shfl_down(v, s);
    if ((tid & 63) == 0) red[tid >> 6] = v;
    __syncthreads();
    if (tid == 0) {
        float tot = 0.f;
        for (int i = 0; i < 8; ++i) tot += red[i];
        out[524288] = 1.25f * sse[0] / ((float)NROWS * (float)CD);
        out[524289] = expf(-tot);
    }
}

extern "C" void kernel_launch(void* const* d_in, const int* in_sizes, int n_in,
                              void* d_out, int out_size, void* d_ws, size_t ws_size,
                              hipStream_t stream) {
    const float* x      = (const float*)d_in[0];
    const float* ec1_w  = (const float*)d_in[1];
    const float* ec1_b  = (const float*)d_in[2];
    const float* ec2_w  = (const float*)d_in[3];
    const float* ec2_b  = (const float*)d_in[4];
    const float* ec3_w  = (const float*)d_in[5];
    const float* ec3_b  = (const float*)d_in[6];
    const float* er1_w1 = (const float*)d_in[7];
    const float* er1_w2 = (const float*)d_in[8];
    const float* er2_w1 = (const float*)d_in[9];
    const float* er2_w2 = (const float*)d_in[10];
    const float* pvq_w  = (const float*)d_in[11];
    const float* pvq_b  = (const float*)d_in[12];
    const float* cbk    = (const float*)d_in[13];
    const float* dc1_w  = (const float*)d_in[14];
    const float* dc1_b  = (const float*)d_in[15];
    const float* dr1_w1 = (const float*)d_in[16];
    const float* dr1_w2 = (const float*)d_in[17];
    const float* dr2_w1 = (const float*)d_in[18];
    const float* dr2_w2 = (const float*)d_in[19];
    const float* dt1_w  = (const float*)d_in[20];
    const float* dt1_b  = (const float*)d_in[21];
    const float* dt2_w  = (const float*)d_in[22];
    const float* dt2_b  = (const float*)d_in[23];
    float* out = (float*)d_out;

    char* ws = (char*)d_ws;
    float* A    = (float*)(ws);                        // 64 MB
    float* Bb   = (float*)(ws + 67108864);             // 64 MB
    char*  smal = ws + 134217728;
    int*   counts = (int*)smal;                        // 2048 B
    float* sse    = (float*)(smal + 2048);             // 4 B
    float* cb2    = (float*)(smal + 4096);             // 2048 B
    short* wf_ec2 = (short*)(smal + 8192);             // 32768 sh
    short* wf_ec3 = wf_ec2 + 32768;                    // 49152 sh
    short* wf_er1 = wf_ec3 + 49152;                    // 12288 sh
    short* wf_er2 = wf_er1 + 12288;
    short* wf_dc1 = wf_er2 + 12288;                    // 24576 sh
    short* wf_dr1 = wf_dc1 + 24576;
    short* wf_dr2 = wf_dr1 + 12288;
    short* wf_dt1 = wf_dr2 + 12288;                    // 32768 sh
    short* cbf_hi = wf_dt1 + 32768;                    // 32768 sh
    short* cbf_lo = cbf_hi + 32768;                    // 32768 sh
    short* w2_er1h = cbf_lo + 32768;                   // 4096 sh each
    short* w2_er1l = w2_er1h + 4096;
    short* w2_er2h = w2_er1l + 4096;
    short* w2_er2l = w2_er2h + 4096;
    short* w2_dr1h = w2_er2l + 4096;
    short* w2_dr1l = w2_dr1h + 4096;
    short* w2_dr2h = w2_dr1l + 4096;
    short* w2_dr2l = w2_dr2h + 4096;
    float* z = Bb;                                     // 32 MB  [B,2048,64]
    float* q = Bb + 8388608;                           // 32 MB  [B,2048,64]

    hipMemsetAsync(smal, 0, 2056, stream);

    // weight / codebook fragment prep (tiny)
    k_wtf<<<dim3(128), 256, 0, stream>>>(ec2_w, wf_ec2, 128, 64, 4, 0);
    k_wtf<<<dim3(192), 256, 0, stream>>>(ec3_w, wf_ec3, 128, 128, 3, 0);
    k_wtf<<<dim3(48), 256, 0, stream>>>(er1_w1, wf_er1, 32, 128, 3, 0);
    k_wtf<<<dim3(48), 256, 0, stream>>>(er2_w1, wf_er2, 32, 128, 3, 0);
    k_wtf<<<dim3(96), 256, 0, stream>>>(dc1_w, wf_dc1, 128, 64, 3, 0);
    k_wtf<<<dim3(48), 256, 0, stream>>>(dr1_w1, wf_dr1, 32, 128, 3, 0);
    k_wtf<<<dim3(48), 256, 0, stream>>>(dr2_w1, wf_dr2, 32, 128, 3, 0);
    k_wtf<<<dim3(128), 256, 0, stream>>>(dt1_w, wf_dt1, 64, 128, 4, 1);
    k_w2f<<<dim3(16), 256, 0, stream>>>(er1_w2, w2_er1h, w2_er1l);
    k_w2f<<<dim3(16), 256, 0, stream>>>(er2_w2, w2_er2h, w2_er2l);
    k_w2f<<<dim3(16), 256, 0, stream>>>(dr1_w2, w2_dr1h, w2_dr1l);
    k_w2f<<<dim3(16), 256, 0, stream>>>(dr2_w2, w2_dr2h, w2_dr2l);
    k_cbf<<<dim3(128), 256, 0, stream>>>(cbk, cbf_hi, cbf_lo);
    k_cb2<<<dim3(2), 256, 0, stream>>>(cbk, cb2);

    // encoder
    k_ec1<<<dim3((NB * CHH * L1) / 256), 256, 0, stream>>>(x, ec1_w, ec1_b, A);
    k_mfconv2<64, 128, 4, 2, 1, L1, false, false, true, true>
        <<<dim3(LQ / 64, 1, NB), 256, 0, stream>>>(A, wf_ec2, ec2_b, Bb);
    k_mfconv2<128, 128, 3, 1, 0, LQ, false, false, true, false>
        <<<dim3(LQ / 64, 1, NB), 256, 0, stream>>>(Bb, wf_ec3, ec3_b, A);
    // fused residual blocks (ping-pong: halo read forbids in-place)
    k_resblk<<<dim3(LQ / 64, 1, NB), 256, 0, stream>>>(A, Bb, wf_er1, w2_er1h, w2_er1l);
    k_resblk<<<dim3(LQ / 64, 1, NB), 256, 0, stream>>>(Bb, A, wf_er2, w2_er2h, w2_er2l);
    k_pvqr<<<dim3(LQ / 64, NB), 256, 0, stream>>>(A, pvq_w, pvq_b, z);

    // vector quantizer (split-precision MFMA argmin + fused gather/SSE/hist)
    k_vqm<<<dim3(NROWS / 256), 256, 0, stream>>>(z, cbf_hi, cbf_lo, cb2, cbk,
                                                 q, counts, sse);

    // decoder
    k_mfconv2<64, 128, 3, 1, 0, LQ, false, true, true, false>
        <<<dim3(LQ / 64, 1, NB), 256, 0, stream>>>(q, wf_dc1, dc1_b, A);
    k_resblk<<<dim3(LQ / 64, 1, NB), 256, 0, stream>>>(A, Bb, wf_dr1, w2_dr1h, w2_dr1l);
    k_resblk<<<dim3(LQ / 64, 1, NB), 256, 0, stream>>>(Bb, A, wf_dr2, w2_dr2h, w2_dr2l);
    k_dt1m<<<dim3(LQ / 64, 1, NB), 256, 0, stream>>>(A, wf_dt1, dt1_b, Bb);
    k_dt2<<<dim3(L1 / 256, NB), 256, 0, stream>>>(Bb, dt2_w, dt2_b, out);

    // scalars
    k_final<<<dim3(1), 512, 0, stream>>>(counts, sse, out);
}

// Round 9
// 617.782 us; speedup vs baseline: 8.5176x; 1.0979x over previous
//
#include <hip/hip_runtime.h>
#include <math.h>

// Problem constants
static constexpr int NB  = 64;     // batch
static constexpr int L0  = 8192;   // input length
static constexpr int L1  = 4096;   // after ec1
static constexpr int LQ  = 2048;   // latent length
static constexpr int CH  = 128;    // hidden H
static constexpr int CHH = 64;     // H/2
static constexpr int CR  = 32;     // residual hidden
static constexpr int CD  = 64;     // codebook dim D
static constexpr int NK  = 512;    // codebook size K
static constexpr int NROWS = NB * LQ;  // 131072 latent vectors

using short8 = __attribute__((ext_vector_type(8))) short;
using f32x4  = __attribute__((ext_vector_type(4))) float;

__device__ inline f32x4 mfma16(short8 a, short8 b, f32x4 c) {
    return __builtin_amdgcn_mfma_f32_16x16x32_bf16(a, b, c, 0, 0, 0);
}

__device__ inline unsigned short bf16rne(float v) {
    unsigned int bb = __builtin_bit_cast(unsigned int, v);
    unsigned int r = (bb + 0x7FFFu + ((bb >> 16) & 1u)) >> 16;
    return (unsigned short)r;
}
__device__ inline float bf2f(unsigned short s) {
    unsigned int u = ((unsigned int)s) << 16;
    return __builtin_bit_cast(float, u);
}

// ---- conv weight->fragment prep: dst [tap][cb][kb][cl*32+hi*8+j] bf16 ----
__global__ __launch_bounds__(256) void k_wtf(const float* __restrict__ src,
                                             short* __restrict__ dst,
                                             int CO, int CI, int K, int iok) {
    int i = blockIdx.x * 256 + threadIdx.x;
    int total = K * CO * CI;
    if (i >= total) return;
    int j  = i & 7;
    int hi = (i >> 3) & 3;
    int cl = (i >> 5) & 15;
    int rest = i >> 9;
    int CIb = CI >> 5, COb = CO >> 4;
    int kb = rest % CIb; rest /= CIb;
    int cb = rest % COb;
    int tap = rest / COb;
    int co = cb * 16 + cl, ci = kb * 32 + hi * 8 + j;
    float v = iok ? src[(ci * CO + co) * K + tap] : src[(co * CI + ci) * K + tap];
    dst[i] = (short)bf16rne(v);
}

// ---- k=1 weight frag prep with hi/lo split: CO=128, CI=32 ----
__global__ __launch_bounds__(256) void k_w2f(const float* __restrict__ src,
                                             short* __restrict__ hi_dst,
                                             short* __restrict__ lo_dst) {
    int i = blockIdx.x * 256 + threadIdx.x;   // 4096
    if (i >= CH * CR) return;
    int j  = i & 7;
    int hi = (i >> 3) & 3;
    int cl = (i >> 5) & 15;
    int cb = i >> 9;
    int co = cb * 16 + cl, ci = hi * 8 + j;
    float v = src[co * CR + ci];
    unsigned short h = bf16rne(v);
    hi_dst[i] = (short)h;
    lo_dst[i] = (short)bf16rne(v - bf2f(h));
}

// ---- pvq weight frag prep with hi/lo split: CO=64 (d), CI=128 ----
__global__ __launch_bounds__(256) void k_pwf(const float* __restrict__ src,
                                             short* __restrict__ hi_dst,
                                             short* __restrict__ lo_dst) {
    int i = blockIdx.x * 256 + threadIdx.x;   // 8192
    if (i >= CD * CH) return;
    int j  = i & 7;
    int hi = (i >> 3) & 3;
    int cl = (i >> 5) & 15;
    int rest = i >> 9;
    int kb = rest & 3, cb = rest >> 2;
    int d = cb * 16 + cl, ci = kb * 32 + hi * 8 + j;
    float v = src[d * CH + ci];
    unsigned short h = bf16rne(v);
    hi_dst[i] = (short)h;
    lo_dst[i] = (short)bf16rne(v - bf2f(h));
}

// ---- codebook A-frag prep, split precision: -2*cb = hi + lo (both bf16) ----
__global__ __launch_bounds__(256) void k_cbf(const float* __restrict__ cb,
                                             short* __restrict__ hi_dst,
                                             short* __restrict__ lo_dst) {
    int i = blockIdx.x * 256 + threadIdx.x;   // 32768
    if (i >= NK * CD) return;
    int j    = i & 7;
    int l    = (i >> 3) & 63;
    int half = (i >> 9) & 1;
    int mt   = i >> 10;
    int cl = l & 15, hi = l >> 4;
    int m = mt * 16 + cl;
    int k = half * 32 + hi * 8 + j;
    float v = -2.f * cb[m * CD + k];
    unsigned short h = bf16rne(v);
    float r = v - bf2f(h);
    hi_dst[i] = (short)h;
    lo_dst[i] = (short)bf16rne(r);
}

// ---------------- ec1: [B,1,8192] -> [B,64,4096], k4 s2 p1, bias+ReLU ----------------
__global__ __launch_bounds__(256) void k_ec1(const float* __restrict__ x,
                                             const float* __restrict__ w,
                                             const float* __restrict__ bias,
                                             float* __restrict__ out) {
    int n = blockIdx.x * 256 + threadIdx.x;
    int t  = n & (L1 - 1);
    int co = (n >> 12) & (CHH - 1);
    int b  = n >> 18;
    const float* xp = x + b * L0;
    float acc = bias[co];
    int p0 = 2 * t - 1;
#pragma unroll
    for (int k = 0; k < 4; ++k) {
        int p = p0 + k;
        if (p >= 0 && p < L0) acc += w[co * 4 + k] * xp[p];
    }
    out[n] = fmaxf(acc, 0.f);
}

// ---------------- MFMA conv v2: bf16 swizzled LDS [t][ci], ds_read_b128 B-frags -------
template <int CIN, int COUT, int NTAPS, int TSTRIDE, int SWS, int LIN,
          bool RELU_IN, bool TRANS_IN, bool HAS_BIAS, bool RELU_OUT>
__global__ __launch_bounds__(256) void k_mfconv2(const float* __restrict__ x,
                                                 const short* __restrict__ wf,
                                                 const float* __restrict__ bias,
                                                 float* __restrict__ out) {
    constexpr int XW = 63 * TSTRIDE + NTAPS;
    constexpr int MR = (COUT == 128) ? 4 : 1;
    constexpr int COb = COUT / 16, CIb = CIN / 32;
    __shared__ unsigned int xsu[CIN * XW / 2];
    int t0 = blockIdx.x * 64;
    int b  = blockIdx.z;
    int tid = threadIdx.x;

    if (TRANS_IN) {
        for (int i = tid; i < XW * (CIN / 2); i += 256) {
            int j = i / (CIN / 2);
            int ci = (i - j * (CIN / 2)) * 2;
            int p = t0 - 1 + j;
            float vx = 0.f, vy = 0.f;
            if (p >= 0 && p < LIN) {
                const float* s = x + ((size_t)b * LIN + p) * CIN + ci;
                vx = s[0]; vy = s[1];
            }
            if (RELU_IN) { vx = fmaxf(vx, 0.f); vy = fmaxf(vy, 0.f); }
            unsigned int u = (__builtin_bit_cast(unsigned int, vx) >> 16)
                           | (__builtin_bit_cast(unsigned int, vy) & 0xFFFF0000u);
            int byte = (j * CIN + ci) * 2;
            byte ^= ((j >> SWS) & 7) << 4;
            xsu[byte >> 2] = u;
        }
    } else {
        for (int i = tid; i < (CIN / 2) * XW; i += 256) {
            int ci2 = i / XW;
            int j = i - ci2 * XW;
            int ci = ci2 * 2;
            int p = t0 * TSTRIDE - 1 + j;
            float vx = 0.f, vy = 0.f;
            if (p >= 0 && p < LIN) {
                const float* s = x + ((size_t)b * CIN + ci) * LIN + p;
                vx = s[0]; vy = s[LIN];
            }
            if (RELU_IN) { vx = fmaxf(vx, 0.f); vy = fmaxf(vy, 0.f); }
            unsigned int u = (__builtin_bit_cast(unsigned int, vx) >> 16)
                           | (__builtin_bit_cast(unsigned int, vy) & 0xFFFF0000u);
            int byte = (j * CIN + ci) * 2;
            byte ^= ((j >> SWS) & 7) << 4;
            xsu[byte >> 2] = u;
        }
    }
    __syncthreads();

    int l  = tid & 63;
    int w  = tid >> 6;
    int cl = l & 15, hi = l >> 4;
    int co_w = (w & 1) * (MR * 16);
    int t_w  = (w >> 1) * 32;

    f32x4 acc[MR][2];
#pragma unroll
    for (int m = 0; m < MR; ++m)
#pragma unroll
        for (int n = 0; n < 2; ++n) acc[m][n] = (f32x4){0.f, 0.f, 0.f, 0.f};

#pragma unroll
    for (int tap = 0; tap < NTAPS; ++tap) {
#pragma unroll
        for (int kb = 0; kb < CIb; ++kb) {
            const short* ap = wf + ((size_t)((tap * COb + co_w / 16) * CIb + kb)) * 512
                            + cl * 32 + hi * 8;
            short8 a[MR];
#pragma unroll
            for (int m = 0; m < MR; ++m)
                a[m] = *reinterpret_cast<const short8*>(ap + (size_t)m * CIb * 512);
            short8 bf[2];
#pragma unroll
            for (int n = 0; n < 2; ++n) {
                int tt = (t_w + n * 16 + cl) * TSTRIDE + tap;
                int byte = (tt * CIN + kb * 32 + hi * 8) * 2;
                byte ^= ((tt >> SWS) & 7) << 4;
                bf[n] = *reinterpret_cast<const short8*>(
                            reinterpret_cast<const char*>(xsu) + byte);
            }
#pragma unroll
            for (int m = 0; m < MR; ++m)
#pragma unroll
                for (int n = 0; n < 2; ++n)
                    acc[m][n] = mfma16(a[m], bf[n], acc[m][n]);
        }
    }

#pragma unroll
    for (int m = 0; m < MR; ++m) {
#pragma unroll
        for (int n = 0; n < 2; ++n) {
#pragma unroll
            for (int r = 0; r < 4; ++r) {
                int co = co_w + m * 16 + hi * 4 + r;
                int t  = t0 + t_w + n * 16 + cl;
                float v = acc[m][n][r];
                if (HAS_BIAS) v += bias[co];
                if (RELU_OUT) v = fmaxf(v, 0.f);
                out[((size_t)b * COUT + co) * LQ + t] = v;
            }
        }
    }
}

// ---------------- dc1 with codebook gather: in = cb[idx[p]], k3 p1, bias ----------------
__global__ __launch_bounds__(256) void k_dc1g(const int* __restrict__ idx,
                                              const float* __restrict__ cb,
                                              const short* __restrict__ wf,
                                              const float* __restrict__ bias,
                                              float* __restrict__ out) {
    constexpr int XW = 66;
    __shared__ unsigned int xsu[CD * XW / 2];
    int t0 = blockIdx.x * 64;
    int b  = blockIdx.z;
    int tid = threadIdx.x;

    for (int i = tid; i < XW * (CD / 2); i += 256) {
        int j = i >> 5;                  // /(CD/2)=32
        int ci = (i & 31) * 2;
        int p = t0 - 1 + j;
        float vx = 0.f, vy = 0.f;
        if (p >= 0 && p < LQ) {
            int id = idx[(size_t)b * LQ + p];
            const float* s = cb + (size_t)id * CD + ci;
            vx = s[0]; vy = s[1];
        }
        unsigned int u = (__builtin_bit_cast(unsigned int, vx) >> 16)
                       | (__builtin_bit_cast(unsigned int, vy) & 0xFFFF0000u);
        int byte = (j * CD + ci) * 2;
        byte ^= (j & 7) << 4;
        xsu[byte >> 2] = u;
    }
    __syncthreads();

    int l  = tid & 63;
    int w  = tid >> 6;
    int cl = l & 15, hi = l >> 4;
    int co_w = (w & 1) * 64;
    int t_w  = (w >> 1) * 32;

    f32x4 acc[4][2];
#pragma unroll
    for (int m = 0; m < 4; ++m)
#pragma unroll
        for (int n = 0; n < 2; ++n) acc[m][n] = (f32x4){0.f, 0.f, 0.f, 0.f};

#pragma unroll
    for (int tap = 0; tap < 3; ++tap) {
#pragma unroll
        for (int kb = 0; kb < 2; ++kb) {
            const short* ap = wf + ((size_t)((tap * 8 + co_w / 16) * 2 + kb)) * 512
                            + cl * 32 + hi * 8;
            short8 a[4];
#pragma unroll
            for (int m = 0; m < 4; ++m)
                a[m] = *reinterpret_cast<const short8*>(ap + (size_t)m * 2 * 512);
            short8 bf[2];
#pragma unroll
            for (int n = 0; n < 2; ++n) {
                int tt = (t_w + n * 16 + cl) + tap;
                int byte = (tt * CD + kb * 32 + hi * 8) * 2;
                byte ^= (tt & 7) << 4;
                bf[n] = *reinterpret_cast<const short8*>(
                            reinterpret_cast<const char*>(xsu) + byte);
            }
#pragma unroll
            for (int m = 0; m < 4; ++m)
#pragma unroll
                for (int n = 0; n < 2; ++n)
                    acc[m][n] = mfma16(a[m], bf[n], acc[m][n]);
        }
    }

#pragma unroll
    for (int m = 0; m < 4; ++m) {
#pragma unroll
        for (int n = 0; n < 2; ++n) {
#pragma unroll
            for (int r = 0; r < 4; ++r) {
                int co = co_w + m * 16 + hi * 4 + r;
                int t  = t0 + t_w + n * 16 + cl;
                out[((size_t)b * CH + co) * LQ + t] = acc[m][n][r] + bias[co];
            }
        }
    }
}

// ---------------- fused residual block: dst = src + W2 . relu(conv3(relu(src))) --------
__global__ __launch_bounds__(256) void k_resblk(const float* __restrict__ src,
                                                float* __restrict__ dst,
                                                const short* __restrict__ wf1,
                                                const short* __restrict__ w2h,
                                                const short* __restrict__ w2l) {
    constexpr int XW = 66;
    __shared__ unsigned int xsu[CH * XW / 2];   // 16896 B
    __shared__ unsigned int hh[64 * 16];        // [t][ciu] hi, 4 KB
    __shared__ unsigned int hl[64 * 16];        // lo, 4 KB
    int t0 = blockIdx.x * 64;
    int b  = blockIdx.z;
    int tid = threadIdx.x;

    for (int i = tid; i < (CH / 2) * XW; i += 256) {
        int ci2 = i / XW;
        int j = i - ci2 * XW;
        int ci = ci2 * 2;
        int p = t0 - 1 + j;
        float vx = 0.f, vy = 0.f;
        if (p >= 0 && p < LQ) {
            const float* s = src + ((size_t)b * CH + ci) * LQ + p;
            vx = fmaxf(s[0], 0.f); vy = fmaxf(s[LQ], 0.f);
        }
        unsigned int u = (__builtin_bit_cast(unsigned int, vx) >> 16)
                       | (__builtin_bit_cast(unsigned int, vy) & 0xFFFF0000u);
        int byte = (j * CH + ci) * 2;
        byte ^= (j & 7) << 4;
        xsu[byte >> 2] = u;
    }
    __syncthreads();

    int l  = tid & 63;
    int w  = tid >> 6;
    int cl = l & 15, hi = l >> 4;
    int co_w1 = (w & 1) * 16;     // h-channel tile base (0 or 16)
    int t_w   = (w >> 1) * 32;    // t base (0..32)

    // ---- stage 1: h = conv3(relu(x)) ----
    f32x4 acc1[2];
    acc1[0] = (f32x4){0.f, 0.f, 0.f, 0.f};
    acc1[1] = (f32x4){0.f, 0.f, 0.f, 0.f};
#pragma unroll
    for (int tap = 0; tap < 3; ++tap) {
#pragma unroll
        for (int kb = 0; kb < 4; ++kb) {
            const short* ap = wf1 + ((size_t)((tap * 2 + (w & 1)) * 4 + kb)) * 512
                            + cl * 32 + hi * 8;
            short8 a = *reinterpret_cast<const short8*>(ap);
#pragma unroll
            for (int n = 0; n < 2; ++n) {
                int tt = (t_w + n * 16 + cl) + tap;
                int byte = (tt * CH + kb * 32 + hi * 8) * 2;
                byte ^= (tt & 7) << 4;
                short8 bf = *reinterpret_cast<const short8*>(
                                reinterpret_cast<const char*>(xsu) + byte);
                acc1[n] = mfma16(a, bf, acc1[n]);
            }
        }
    }

    // relu + hi/lo split -> h LDS [t][ciu] (u32 = 2 bf16), swizzle idx ^= (t&3)<<2
#pragma unroll
    for (int n = 0; n < 2; ++n) {
        int t = t_w + n * 16 + cl;
#pragma unroll
        for (int rp = 0; rp < 2; ++rp) {
            float v0 = fmaxf(acc1[n][2 * rp], 0.f);
            float v1 = fmaxf(acc1[n][2 * rp + 1], 0.f);
            unsigned short h0 = bf16rne(v0), h1 = bf16rne(v1);
            unsigned short l0 = bf16rne(v0 - bf2f(h0)), l1 = bf16rne(v1 - bf2f(h1));
            int ciu = (co_w1 >> 1) + hi * 2 + rp;
            int idx = t * 16 + (ciu ^ ((t & 3) << 2));
            hh[idx] = (unsigned int)h0 | ((unsigned int)h1 << 16);
            hl[idx] = (unsigned int)l0 | ((unsigned int)l1 << 16);
        }
    }
    __syncthreads();

    // ---- stage 2: res = W2 . relu(h), split precision; dst = src + res ----
    int co2_w = (w & 1) * 64;
    short8 bh[2], bl[2];
#pragma unroll
    for (int n2 = 0; n2 < 2; ++n2) {
        int t = t_w + n2 * 16 + cl;
        int idx = t * 16 + ((hi * 4) ^ ((t & 3) << 2));
        bh[n2] = *reinterpret_cast<const short8*>(&hh[idx]);
        bl[n2] = *reinterpret_cast<const short8*>(&hl[idx]);
    }
#pragma unroll
    for (int m2 = 0; m2 < 4; ++m2) {
        int co2 = co2_w + m2 * 16;
        const short* aph = w2h + (co2 / 16) * 512 + cl * 32 + hi * 8;
        const short* apl = w2l + (co2 / 16) * 512 + cl * 32 + hi * 8;
        short8 ah = *reinterpret_cast<const short8*>(aph);
        short8 al = *reinterpret_cast<const short8*>(apl);
#pragma unroll
        for (int n2 = 0; n2 < 2; ++n2) {
            f32x4 acc = (f32x4){0.f, 0.f, 0.f, 0.f};
            acc = mfma16(ah, bl[n2], acc);
            acc = mfma16(al, bh[n2], acc);
            acc = mfma16(ah, bh[n2], acc);
            int t = t0 + t_w + n2 * 16 + cl;
#pragma unroll
            for (int r = 0; r < 4; ++r) {
                int co = co2 + hi * 4 + r;
                size_t off = ((size_t)b * CH + co) * LQ + t;
                dst[off] = src[off] + acc[r];
            }
        }
    }
}

// ---------------- dt1 MFMA v2: ConvT 128->64 k4 s2 p1, relu(in), relu(out) -------------
__global__ __launch_bounds__(256) void k_dt1m(const float* __restrict__ x,
                                              const short* __restrict__ wf,  // IOK frags
                                              const float* __restrict__ bias,
                                              float* __restrict__ out) {
    constexpr int XW = 66;
    __shared__ unsigned int xsu[CH * XW / 2];
    int t0 = blockIdx.x * 64;     // u-range base
    int b  = blockIdx.z;
    int tid = threadIdx.x;
    for (int i = tid; i < (CH / 2) * XW; i += 256) {
        int ci2 = i / XW;
        int j = i - ci2 * XW;
        int ci = ci2 * 2;
        int p = t0 - 1 + j;
        float vx = 0.f, vy = 0.f;
        if (p >= 0 && p < LQ) {
            const float* s = x + ((size_t)b * CH + ci) * LQ + p;
            vx = fmaxf(s[0], 0.f); vy = fmaxf(s[LQ], 0.f);
        }
        unsigned int u = (__builtin_bit_cast(unsigned int, vx) >> 16)
                       | (__builtin_bit_cast(unsigned int, vy) & 0xFFFF0000u);
        int byte = (j * CH + ci) * 2;
        byte ^= (j & 7) << 4;
        xsu[byte >> 2] = u;
    }
    __syncthreads();

    int l  = tid & 63;
    int w  = tid >> 6;
    int cl = l & 15, hi = l >> 4;
    int co_w = (w & 1) * 32;
    int u_w  = (w >> 1) * 32;

    f32x4 ae[2][2], ao[2][2];
#pragma unroll
    for (int m = 0; m < 2; ++m)
#pragma unroll
        for (int n = 0; n < 2; ++n) {
            ae[m][n] = (f32x4){0.f, 0.f, 0.f, 0.f};
            ao[m][n] = (f32x4){0.f, 0.f, 0.f, 0.f};
        }

    const int TK[4] = {1, 3, 0, 2};
    const int TO[4] = {1, 0, 2, 1};
#pragma unroll
    for (int te = 0; te < 4; ++te) {
        int k = TK[te], off = TO[te];
#pragma unroll
        for (int kb = 0; kb < 4; ++kb) {
            const short* ap = wf + (size_t)((k * 4 + co_w / 16) * 4 + kb) * 512
                            + cl * 32 + hi * 8;
            short8 a[2];
#pragma unroll
            for (int m = 0; m < 2; ++m)
                a[m] = *reinterpret_cast<const short8*>(ap + (size_t)m * 4 * 512);
            short8 bf[2];
#pragma unroll
            for (int n = 0; n < 2; ++n) {
                int tt = u_w + n * 16 + cl + off;
                int byte = (tt * CH + kb * 32 + hi * 8) * 2;
                byte ^= (tt & 7) << 4;
                bf[n] = *reinterpret_cast<const short8*>(
                            reinterpret_cast<const char*>(xsu) + byte);
            }
#pragma unroll
            for (int m = 0; m < 2; ++m)
#pragma unroll
                for (int n = 0; n < 2; ++n) {
                    if (te < 2) ae[m][n] = mfma16(a[m], bf[n], ae[m][n]);
                    else        ao[m][n] = mfma16(a[m], bf[n], ao[m][n]);
                }
        }
    }

#pragma unroll
    for (int m = 0; m < 2; ++m) {
#pragma unroll
        for (int n = 0; n < 2; ++n) {
#pragma unroll
            for (int r = 0; r < 4; ++r) {
                int co = co_w + m * 16 + hi * 4 + r;
                int u  = t0 + u_w + n * 16 + cl;
                float bv = bias[co];
                float2 rr;
                rr.x = fmaxf(ae[m][n][r] + bv, 0.f);
                rr.y = fmaxf(ao[m][n][r] + bv, 0.f);
                *reinterpret_cast<float2*>(&out[((size_t)b * CHH + co) * L1 + 2 * u]) = rr;
            }
        }
    }
}

// ---------------- pvq via split-precision MFMA: z[b,t,d], fp32-accurate ----------------
__global__ __launch_bounds__(256) void k_pvqm(const float* __restrict__ x,
                                              const short* __restrict__ pwh,
                                              const short* __restrict__ pwl,
                                              const float* __restrict__ bias,
                                              float* __restrict__ z) {
    __shared__ unsigned int xh[(CH / 2) * 64];   // 16 KB
    __shared__ unsigned int xl[(CH / 2) * 64];   // 16 KB
    int t0 = blockIdx.x * 64;
    int b  = blockIdx.y;
    int tid = threadIdx.x;

    for (int i = tid; i < (CH / 2) * 64; i += 256) {
        int ci2 = i >> 6;
        int t = i & 63;
        int ci = ci2 * 2;
        const float* s = x + ((size_t)b * CH + ci) * LQ + t0 + t;
        float vx = fmaxf(s[0], 0.f);
        float vy = fmaxf(s[LQ], 0.f);
        unsigned short hx = bf16rne(vx), hy = bf16rne(vy);
        unsigned short lx = bf16rne(vx - bf2f(hx)), ly = bf16rne(vy - bf2f(hy));
        int byte = (t * CH + ci) * 2;
        byte ^= (t & 7) << 4;
        xh[byte >> 2] = (unsigned int)hx | ((unsigned int)hy << 16);
        xl[byte >> 2] = (unsigned int)lx | ((unsigned int)ly << 16);
    }
    __syncthreads();

    int l  = tid & 63;
    int w  = tid >> 6;                 // wave = d-tile (4 x 16 = 64 d)
    int cl = l & 15, hi = l >> 4;

    float4 bv4 = *reinterpret_cast<const float4*>(&bias[w * 16 + hi * 4]);
    f32x4 acc[4];
#pragma unroll
    for (int nt = 0; nt < 4; ++nt) acc[nt] = (f32x4){bv4.x, bv4.y, bv4.z, bv4.w};

#pragma unroll
    for (int kb = 0; kb < 4; ++kb) {
        const short* aph = pwh + ((size_t)(w * 4 + kb)) * 512 + cl * 32 + hi * 8;
        const short* apl = pwl + ((size_t)(w * 4 + kb)) * 512 + cl * 32 + hi * 8;
        short8 ah = *reinterpret_cast<const short8*>(aph);
        short8 al = *reinterpret_cast<const short8*>(apl);
#pragma unroll
        for (int nt = 0; nt < 4; ++nt) {
            int tt = nt * 16 + cl;
            int byte = (tt * CH + kb * 32 + hi * 8) * 2;
            byte ^= (tt & 7) << 4;
            short8 bhf = *reinterpret_cast<const short8*>(
                             reinterpret_cast<const char*>(xh) + byte);
            short8 blf = *reinterpret_cast<const short8*>(
                             reinterpret_cast<const char*>(xl) + byte);
            acc[nt] = mfma16(ah, blf, acc[nt]);
            acc[nt] = mfma16(al, bhf, acc[nt]);
            acc[nt] = mfma16(ah, bhf, acc[nt]);
        }
    }

#pragma unroll
    for (int nt = 0; nt < 4; ++nt) {
        int t = t0 + nt * 16 + cl;
        float4 o;
        o.x = acc[nt][0]; o.y = acc[nt][1]; o.z = acc[nt][2]; o.w = acc[nt][3];
        *reinterpret_cast<float4*>(&z[((size_t)b * LQ + t) * CD + w * 16 + hi * 4]) = o;
    }
}

// ---------------- cb2[k] = |codebook_k|^2 ----------------
__global__ __launch_bounds__(256) void k_cb2(const float* __restrict__ cb,
                                             float* __restrict__ cb2) {
    int k = blockIdx.x * 256 + threadIdx.x;
    if (k >= NK) return;
    const float* r = cb + k * CD;
    float s = 0.f;
#pragma unroll 8
    for (int i = 0; i < CD; ++i) s += r[i] * r[i];
    cb2[k] = s;
}

// ---------------- VQ via split-precision MFMA: scores = |c|^2 - 2 z.c ----------------
__global__ __launch_bounds__(256) void k_vqm(const float* __restrict__ z,
                                             const short* __restrict__ cbf_hi,
                                             const short* __restrict__ cbf_lo,
                                             const float* __restrict__ cb2,
                                             const float* __restrict__ cb,
                                             int* __restrict__ idxout,
                                             int* __restrict__ counts,
                                             float* __restrict__ sse) {
    __shared__ float c2l[NK];         // 2 KB
    __shared__ int   hist[NK];        // 2 KB
    int tid = threadIdx.x;
    int l   = tid & 63;
    int w   = tid >> 6;
    int cl  = l & 15, hi = l >> 4;
    int wrow0 = blockIdx.x * 256 + w * 64;

    for (int i = tid; i < NK; i += 256) { c2l[i] = cb2[i]; hist[i] = 0; }
    __syncthreads();

    // load z fragments, split hi/lo (RNE)
    short8 bh[4][2], bl[4][2];
#pragma unroll
    for (int nt = 0; nt < 4; ++nt) {
        int row = wrow0 + nt * 16 + cl;
        const float* zr = z + (size_t)row * CD;
#pragma unroll
        for (int half = 0; half < 2; ++half) {
            const float4* p4 = reinterpret_cast<const float4*>(zr + half * 32 + hi * 8);
            float4 v0 = p4[0], v1 = p4[1];
            float vs[8] = {v0.x, v0.y, v0.z, v0.w, v1.x, v1.y, v1.z, v1.w};
            short8 sh, sl;
#pragma unroll
            for (int j = 0; j < 8; ++j) {
                unsigned short h = bf16rne(vs[j]);
                float r = vs[j] - bf2f(h);
                sh[j] = (short)h;
                sl[j] = (short)bf16rne(r);
            }
            bh[nt][half] = sh;
            bl[nt][half] = sl;
        }
    }

    float bscore[4];
    int   bidx[4];
#pragma unroll
    for (int nt = 0; nt < 4; ++nt) { bscore[nt] = 1e30f; bidx[nt] = 0; }

#pragma unroll 4
    for (int mt = 0; mt < 32; ++mt) {
        short8 ah0 = *reinterpret_cast<const short8*>(cbf_hi + (mt * 2 + 0) * 512 + l * 8);
        short8 ah1 = *reinterpret_cast<const short8*>(cbf_hi + (mt * 2 + 1) * 512 + l * 8);
        short8 al0 = *reinterpret_cast<const short8*>(cbf_lo + (mt * 2 + 0) * 512 + l * 8);
        short8 al1 = *reinterpret_cast<const short8*>(cbf_lo + (mt * 2 + 1) * 512 + l * 8);
        float4 c2v = *reinterpret_cast<const float4*>(&c2l[mt * 16 + hi * 4]);
        f32x4 cin = (f32x4){c2v.x, c2v.y, c2v.z, c2v.w};
        int mbase = mt * 16 + hi * 4;
#pragma unroll
        for (int nt = 0; nt < 4; ++nt) {
            f32x4 acc = mfma16(al0, bh[nt][0], cin);    // A_lo . z_hi
            acc = mfma16(al1, bh[nt][1], acc);
            acc = mfma16(ah0, bl[nt][0], acc);          // A_hi . z_lo
            acc = mfma16(ah1, bl[nt][1], acc);
            acc = mfma16(ah0, bh[nt][0], acc);          // A_hi . z_hi
            acc = mfma16(ah1, bh[nt][1], acc);
#pragma unroll
            for (int r = 0; r < 4; ++r) {
                float s = acc[r];
                bool better = s < bscore[nt];
                bscore[nt] = better ? s : bscore[nt];
                bidx[nt]   = better ? (mbase + r) : bidx[nt];
            }
        }
    }

    // cross-lane argmin + fused epilogue (idx write, SSE, hist)
    float err = 0.f;
#pragma unroll
    for (int nt = 0; nt < 4; ++nt) {
        float s = bscore[nt];
        int   id = bidx[nt];
#pragma unroll
        for (int off = 16; off <= 32; off <<= 1) {
            float s2 = __shfl_xor(s, off);
            int   i2 = __shfl_xor(id, off);
            bool take = (s2 < s) || (s2 == s && i2 < id);
            s  = take ? s2 : s;
            id = take ? i2 : id;
        }
        int row = wrow0 + nt * 16 + cl;
        if (hi == 0) idxout[row] = id;
        const float4* cbr = reinterpret_cast<const float4*>(cb + (size_t)id * CD);
        float4 q0 = cbr[hi * 2];
        float4 q1 = cbr[hi * 2 + 1];
        float4 q2 = cbr[8 + hi * 2];
        float4 q3 = cbr[8 + hi * 2 + 1];
        float qv[16] = {q0.x, q0.y, q0.z, q0.w, q1.x, q1.y, q1.z, q1.w,
                        q2.x, q2.y, q2.z, q2.w, q3.x, q3.y, q3.z, q3.w};
#pragma unroll
        for (int half = 0; half < 2; ++half) {
#pragma unroll
            for (int j = 0; j < 8; ++j) {
                float zv = bf2f((unsigned short)bh[nt][half][j])
                         + bf2f((unsigned short)bl[nt][half][j]);
                float d = qv[half * 8 + j] - zv;
                err = fmaf(d, d, err);
            }
        }
        if (hi == 0) atomicAdd(&hist[id], 1);
    }
#pragma unroll
    for (int s = 32; s > 0; s >>= 1) err += __shfl_xor(err, s);
    if (l == 0) atomicAdd(sse, err);

    __syncthreads();
    for (int i = tid; i < NK; i += 256) {
        int h = hist[i];
        if (h) atomicAdd(&counts[i], h);
    }
}

// ---------------- dt2: ConvT 64->1 k4 s2 p1 -> recon ----------------
__global__ __launch_bounds__(256) void k_dt2(const float* __restrict__ x,
                                             const float* __restrict__ w,
                                             const float* __restrict__ bias,
                                             float* __restrict__ out) {
    int u = blockIdx.x * 256 + threadIdx.x;
    int b = blockIdx.y;
    const float* xp = x + (size_t)b * CHH * L1 + u;
    float bv = bias[0];
    float ae = bv, ao = bv;
    for (int ci = 0; ci < CHH; ++ci) {
        const float* xr = xp + ci * L1;
        float xm  = (u >= 1) ? xr[-1] : 0.f;
        float x0  = xr[0];
        float xp1 = (u < L1 - 1) ? xr[1] : 0.f;
        const float* wc = w + ci * 4;
        ae += wc[1] * x0 + wc[3] * xm;
        ao += wc[0] * xp1 + wc[2] * x0;
    }
    reinterpret_cast<float2*>(out + (size_t)b * L0)[u] = make_float2(ae, ao);
}

// ---------------- finalize: vq_loss + perplexity ----------------
__global__ __launch_bounds__(512) void k_final(const int* __restrict__ counts,
                                               const float* __restrict__ sse,
                                               float* __restrict__ out) {
    __shared__ float red[8];
    int tid = threadIdx.x;
    float p = (float)counts[tid] * (1.f / (float)NROWS);
    float v = p * logf(p + 1e-10f);
#pragma unroll
    for (int s = 32; s > 0; s >>= 1) v += __shfl_down(v, s);
    if ((tid & 63) == 0) red[tid >> 6] = v;
    __syncthreads();
    if (tid == 0) {
        float tot = 0.f;
        for (int i = 0; i < 8; ++i) tot += red[i];
        out[524288] = 1.25f * sse[0] / ((float)NROWS * (float)CD);
        out[524289] = expf(-tot);
    }
}

extern "C" void kernel_launch(void* const* d_in, const int* in_sizes, int n_in,
                              void* d_out, int out_size, void* d_ws, size_t ws_size,
                              hipStream_t stream) {
    const float* x      = (const float*)d_in[0];
    const float* ec1_w  = (const float*)d_in[1];
    const float* ec1_b  = (const float*)d_in[2];
    const float* ec2_w  = (const float*)d_in[3];
    const float* ec2_b  = (const float*)d_in[4];
    const float* ec3_w  = (const float*)d_in[5];
    const float* ec3_b  = (const float*)d_in[6];
    const float* er1_w1 = (const float*)d_in[7];
    const float* er1_w2 = (const float*)d_in[8];
    const float* er2_w1 = (const float*)d_in[9];
    const float* er2_w2 = (const float*)d_in[10];
    const float* pvq_w  = (const float*)d_in[11];
    const float* pvq_b  = (const float*)d_in[12];
    const float* cbk    = (const float*)d_in[13];
    const float* dc1_w  = (const float*)d_in[14];
    const float* dc1_b  = (const float*)d_in[15];
    const float* dr1_w1 = (const float*)d_in[16];
    const float* dr1_w2 = (const float*)d_in[17];
    const float* dr2_w1 = (const float*)d_in[18];
    const float* dr2_w2 = (const float*)d_in[19];
    const float* dt1_w  = (const float*)d_in[20];
    const float* dt1_b  = (const float*)d_in[21];
    const float* dt2_w  = (const float*)d_in[22];
    const float* dt2_b  = (const float*)d_in[23];
    float* out = (float*)d_out;

    char* ws = (char*)d_ws;
    float* A    = (float*)(ws);                        // 64 MB
    float* Bb   = (float*)(ws + 67108864);             // 64 MB
    char*  smal = ws + 134217728;
    int*   counts = (int*)smal;                        // 2048 B
    float* sse    = (float*)(smal + 2048);             // 4 B
    float* cb2    = (float*)(smal + 4096);             // 2048 B
    short* wf_ec2 = (short*)(smal + 8192);             // 32768 sh
    short* wf_ec3 = wf_ec2 + 32768;                    // 49152 sh
    short* wf_er1 = wf_ec3 + 49152;                    // 12288 sh
    short* wf_er2 = wf_er1 + 12288;
    short* wf_dc1 = wf_er2 + 12288;                    // 24576 sh
    short* wf_dr1 = wf_dc1 + 24576;
    short* wf_dr2 = wf_dr1 + 12288;
    short* wf_dt1 = wf_dr2 + 12288;                    // 32768 sh
    short* cbf_hi = wf_dt1 + 32768;                    // 32768 sh
    short* cbf_lo = cbf_hi + 32768;                    // 32768 sh
    short* w2_er1h = cbf_lo + 32768;                   // 4096 sh each
    short* w2_er1l = w2_er1h + 4096;
    short* w2_er2h = w2_er1l + 4096;
    short* w2_er2l = w2_er2h + 4096;
    short* w2_dr1h = w2_er2l + 4096;
    short* w2_dr1l = w2_dr1h + 4096;
    short* w2_dr2h = w2_dr1l + 4096;
    short* w2_dr2l = w2_dr2h + 4096;
    short* pw_hi   = w2_dr2l + 4096;                   // 8192 sh
    short* pw_lo   = pw_hi + 8192;                     // 8192 sh
    float* z = Bb;                                     // 32 MB  [B,2048,64]
    int*   idxv = (int*)((char*)Bb + 33554432);        // 512 KB (dead after dc1)

    hipMemsetAsync(smal, 0, 2056, stream);

    // weight / codebook fragment prep (tiny)
    k_wtf<<<dim3(128), 256, 0, stream>>>(ec2_w, wf_ec2, 128, 64, 4, 0);
    k_wtf<<<dim3(192), 256, 0, stream>>>(ec3_w, wf_ec3, 128, 128, 3, 0);
    k_wtf<<<dim3(48), 256, 0, stream>>>(er1_w1, wf_er1, 32, 128, 3, 0);
    k_wtf<<<dim3(48), 256, 0, stream>>>(er2_w1, wf_er2, 32, 128, 3, 0);
    k_wtf<<<dim3(96), 256, 0, stream>>>(dc1_w, wf_dc1, 128, 64, 3, 0);
    k_wtf<<<dim3(48), 256, 0, stream>>>(dr1_w1, wf_dr1, 32, 128, 3, 0);
    k_wtf<<<dim3(48), 256, 0, stream>>>(dr2_w1, wf_dr2, 32, 128, 3, 0);
    k_wtf<<<dim3(128), 256, 0, stream>>>(dt1_w, wf_dt1, 64, 128, 4, 1);
    k_w2f<<<dim3(16), 256, 0, stream>>>(er1_w2, w2_er1h, w2_er1l);
    k_w2f<<<dim3(16), 256, 0, stream>>>(er2_w2, w2_er2h, w2_er2l);
    k_w2f<<<dim3(16), 256, 0, stream>>>(dr1_w2, w2_dr1h, w2_dr1l);
    k_w2f<<<dim3(16), 256, 0, stream>>>(dr2_w2, w2_dr2h, w2_dr2l);
    k_pwf<<<dim3(32), 256, 0, stream>>>(pvq_w, pw_hi, pw_lo);
    k_cbf<<<dim3(128), 256, 0, stream>>>(cbk, cbf_hi, cbf_lo);
    k_cb2<<<dim3(2), 256, 0, stream>>>(cbk, cb2);

    // encoder
    k_ec1<<<dim3((NB * CHH * L1) / 256), 256, 0, stream>>>(x, ec1_w, ec1_b, A);
    k_mfconv2<64, 128, 4, 2, 1, L1, false, false, true, true>
        <<<dim3(LQ / 64, 1, NB), 256, 0, stream>>>(A, wf_ec2, ec2_b, Bb);
    k_mfconv2<128, 128, 3, 1, 0, LQ, false, false, true, false>
        <<<dim3(LQ / 64, 1, NB), 256, 0, stream>>>(Bb, wf_ec3, ec3_b, A);
    // fused residual blocks (ping-pong: halo read forbids in-place)
    k_resblk<<<dim3(LQ / 64, 1, NB), 256, 0, stream>>>(A, Bb, wf_er1, w2_er1h, w2_er1l);
    k_resblk<<<dim3(LQ / 64, 1, NB), 256, 0, stream>>>(Bb, A, wf_er2, w2_er2h, w2_er2l);
    k_pvqm<<<dim3(LQ / 64, NB), 256, 0, stream>>>(A, pw_hi, pw_lo, pvq_b, z);

    // vector quantizer (split-precision MFMA argmin + fused idx/SSE/hist)
    k_vqm<<<dim3(NROWS / 256), 256, 0, stream>>>(z, cbf_hi, cbf_lo, cb2, cbk,
                                                 idxv, counts, sse);

    // decoder
    k_dc1g<<<dim3(LQ / 64, 1, NB), 256, 0, stream>>>(idxv, cbk, wf_dc1, dc1_b, A);
    k_resblk<<<dim3(LQ / 64, 1, NB), 256, 0, stream>>>(A, Bb, wf_dr1, w2_dr1h, w2_dr1l);
    k_resblk<<<dim3(LQ / 64, 1, NB), 256, 0, stream>>>(Bb, A, wf_dr2, w2_dr2h, w2_dr2l);
    k_dt1m<<<dim3(LQ / 64, 1, NB), 256, 0, stream>>>(A, wf_dt1, dt1_b, Bb);
    k_dt2<<<dim3(L1 / 256, NB), 256, 0, stream>>>(Bb, dt2_w, dt2_b, out);

    // scalars
    k_final<<<dim3(1), 512, 0, stream>>>(counts, sse, out);
}